// Round 8
// baseline (713.396 us; speedup 1.0000x reference)
//
#include <hip/hip_runtime.h>
#include <math.h>

typedef __attribute__((ext_vector_type(8))) short  short8;
typedef __attribute__((ext_vector_type(4))) float  f32x4;

// Problem constants: N=200000, E=100000, H=100, R=172, T=100
static constexpr int H     = 100;
static constexpr int RD    = 172;
static constexpr int WK    = 472;            // w_ih K
// Padded K layout (8-col chunks), chunk index c:
//  c [0,13)   mem[node]  (msg part; has-masked copy of hh chunks)
//  c [13,26)  mem[other]
//  c [26,48)  raw_msg
//  c [48,64)  time-enc
//  c [64,80)  mem[node]  (hh part, always present)
static constexpr int NKS   = 20;             // K-steps of 32 (KTOT=640)
static constexpr int MB    = 48;             // nodes per tile
static constexpr int GRPS  = 3;              // 16-row groups
static constexpr int BLK   = 448;            // 7 waves
static constexpr int SLOTS = 64;             // 16B slots per (grp,ks) tile
static constexpr int TPB   = 4;              // tiles per block (pipelined)
static constexpr int ABUF  = GRPS * NKS * SLOTS * 8;   // ushorts per A buffer (30720)
// B tiles: [0,7) r (w_hh folded), [7,14) z (folded), [14,21) n-ih (ks<16), [21,28) n-hh (ks>=16)
static constexpr int NTT   = 28;
static constexpr int BPK_N = NTT * NKS * 64 * 8;   // 286720 bf16

__device__ inline unsigned short f2bf(float x) {
    union { float f; unsigned u; } v; v.f = x;
    return (unsigned short)((v.u + 0x7FFFu + ((v.u >> 16) & 1u)) >> 16);
}
__device__ inline float bf2f(unsigned short b) {
    union { unsigned u; float f; } v; v.u = ((unsigned)b) << 16;
    return v.f;
}
__device__ inline unsigned pkbf(float a, float b) {
    unsigned r;
    asm("v_cvt_pk_bf16_f32 %0, %1, %2" : "=v"(r) : "v"(a), "v"(b));
    return r;
}
__device__ inline f32x4 mfma16(short8 a, short8 b, f32x4 c) {
    return __builtin_amdgcn_mfma_f32_16x16x32_bf16(a, b, c, 0, 0, 0);
}
__device__ inline float4 ld4g(const float* base, int lc, int limit) {
    if (lc + 4 <= limit) return *(const float4*)(base + lc);
    return make_float4(0.f, 0.f, 0.f, 0.f);
}
__device__ inline void pipe_barrier() {
    __builtin_amdgcn_sched_barrier(0);
    asm volatile("s_waitcnt lgkmcnt(0)" ::: "memory");
    __builtin_amdgcn_sched_barrier(0);
    __builtin_amdgcn_s_barrier();
    __builtin_amdgcn_sched_barrier(0);
}

// ---------------- aggregation kernels ----------------
__global__ __launch_bounds__(256) void k_init(int* __restrict__ maxt, int* __restrict__ win, int N) {
    int i = blockIdx.x * blockDim.x + threadIdx.x;
    if (i < N) { maxt[i] = (int)0x80000000; win[i] = -1; }
}

__global__ __launch_bounds__(256) void k_maxt(const int* __restrict__ src, const int* __restrict__ dst,
                                              const int* __restrict__ t, int* __restrict__ maxt, int E) {
    int j = blockIdx.x * blockDim.x + threadIdx.x;
    if (j < E) {
        int tj = t[j];
        atomicMax(&maxt[src[j]], tj);
        atomicMax(&maxt[dst[j]], tj);
    }
}

__global__ __launch_bounds__(256) void k_win(const int* __restrict__ src, const int* __restrict__ dst,
                                             const int* __restrict__ t, const int* __restrict__ maxt,
                                             int* __restrict__ win, int E) {
    int j = blockIdx.x * blockDim.x + threadIdx.x;
    if (j < E) {
        int tj = t[j];
        int s = src[j], d = dst[j];
        if (maxt[s] == tj) atomicMax(&win[s], j);
        if (maxt[d] == tj) atomicMax(&win[d], j + E);
    }
}

// ---------------- weight prep ----------------
__global__ __launch_bounds__(256) void k_prep(const float* __restrict__ w_ih, const float* __restrict__ w_hh,
                                              unsigned short* __restrict__ B) {
    int idx = blockIdx.x * 256 + threadIdx.x;
    if (idx >= BPK_N) return;
    int jj   = idx & 7;
    int lane = (idx >> 3) & 63;
    int rest = idx >> 9;          // tile*NKS + ks
    int ks   = rest % NKS;
    int tile = rest / NKS;
    int kk   = ks * 32 + ((lane >> 4) << 3) + jj;
    float v = 0.f;
    if (tile < 21) {
        int gate = tile / 7;
        int tcol = (tile % 7) * 16 + (lane & 15);
        if (tcol < 100) {
            if (kk < 512) {
                int col = -1;
                if (kk < 100)                   col = kk;          // mem[node]
                else if (kk >= 104 && kk < 204) col = kk - 4;      // mem[other]
                else if (kk >= 208 && kk < 380) col = kk - 8;      // raw
                else if (kk >= 384 && kk < 484) col = kk - 12;     // tenc
                if (col >= 0) v = w_ih[(gate * 100 + tcol) * WK + col];
            } else {
                int khh = kk - 512;
                if (gate < 2 && khh < 100)                          // fold w_hh for r,z
                    v = w_hh[(gate * 100 + tcol) * H + khh];
            }
        }
    } else {
        int tcol = (tile - 21) * 16 + (lane & 15);
        int khh  = kk - 512;
        if (tcol < 100 && khh >= 0 && khh < 100)
            v = w_hh[(200 + tcol) * H + khh];
    }
    B[idx] = f2bf(v);
}

// ---------------- staging helpers ----------------
__device__ inline void issue_loads(int lt, int tid, int node_base, int N,
                                   const int* s_j, const int* s_other, const int* s_has,
                                   const float* memory, const float* raw_msg,
                                   float4 (&va)[8], float4 (&vb)[8])
{
    if (tid >= 432) return;
    const int nl = tid % 48, c0 = tid / 48;
    const int node  = node_base + nl;
    const bool valid = node < N;
    const int has   = s_has[lt * MB + nl];
    const float* memN = memory + (size_t)node * H;
    const float* memO = memory + (size_t)s_other[lt * MB + nl] * H;
    const float* rawJ = raw_msg + (size_t)s_j[lt * MB + nl] * RD;
#pragma unroll
    for (int it = 0; it < 8; ++it) {
        const int cc = c0 + it * 9;
        va[it] = make_float4(0.f, 0.f, 0.f, 0.f); vb[it] = va[it];
        if (cc < 67) {
            const int c = cc + 13, kb = c * 8;
            if (c < 26)      { if (has)  { va[it] = ld4g(memO, kb - 104, 100); vb[it] = ld4g(memO, kb - 100, 100); } }
            else if (c < 48) { if (has)  { va[it] = ld4g(rawJ, kb - 208, RD ); vb[it] = ld4g(rawJ, kb - 204, RD ); } }
            else if (c < 64) { /* tenc computed at write time */ }
            else             { if (valid){ va[it] = ld4g(memN, kb - 512, 100); vb[it] = ld4g(memN, kb - 508, 100); } }
        }
    }
}

__device__ inline void cvt_write(int lt, int tid, unsigned short* __restrict__ buf,
                                 const int* s_has, const float* s_dt,
                                 const float* te_w, const float* te_b,
                                 float4 (&va)[8], float4 (&vb)[8])
{
    if (tid >= 432) return;
    const int nl = tid % 48, c0 = tid / 48;
    const int has = s_has[lt * MB + nl];
    const float dt = s_dt[lt * MB + nl];
    const int grp = nl >> 4, row = nl & 15;
#pragma unroll
    for (int it = 0; it < 8; ++it) {
        const int cc = c0 + it * 9;
        if (cc >= 67) continue;
        const int c = cc + 13;
        if (c >= 48 && c < 64) {                  // tenc: pure VALU, no global loads
            if (has) {
                const int lc = c * 8 - 384;
                float vv[8];
#pragma unroll
                for (int q = 0; q < 8; ++q) {
                    int col = lc + q;
                    vv[q] = (col < 100) ? __cosf(fmaf(dt, te_w[col], te_b[col])) : 0.f;
                }
                va[it] = make_float4(vv[0], vv[1], vv[2], vv[3]);
                vb[it] = make_float4(vv[4], vv[5], vv[6], vv[7]);
            }
        }
        int4 sv;
        sv.x = (int)pkbf(va[it].x, va[it].y);
        sv.y = (int)pkbf(va[it].z, va[it].w);
        sv.z = (int)pkbf(vb[it].x, vb[it].y);
        sv.w = (int)pkbf(vb[it].z, vb[it].w);
        {
            const int ks = c >> 2, sub = c & 3;
            const int slot = sub * 16 + (row ^ (sub << 2));
            *(int4*)&buf[((grp * NKS + ks) * SLOTS + slot) * 8] = sv;
        }
        if (c >= 64 && c < 77) {                  // msg copy of mem[node], has-masked
            int4 sm_;
            sm_.x = has ? sv.x : 0; sm_.y = has ? sv.y : 0;
            sm_.z = has ? sv.z : 0; sm_.w = has ? sv.w : 0;
            const int cm = c - 64;
            const int ks = cm >> 2, sub = cm & 3;
            const int slot = sub * 16 + (row ^ (sub << 2));
            *(int4*)&buf[((grp * NKS + ks) * SLOTS + slot) * 8] = sm_;
        }
    }
}

// ---------------- fused GRU: pipelined bf16-MFMA over TPB tiles ----------------
__global__ __launch_bounds__(BLK, 2) void k_gru(
    const int* __restrict__ src, const int* __restrict__ dst, const int* __restrict__ t,
    const float* __restrict__ raw_msg, const float* __restrict__ memory,
    const int* __restrict__ last_update, const float* __restrict__ te_w,
    const float* __restrict__ te_b, const float* __restrict__ b_ih,
    const float* __restrict__ b_hh, const int* __restrict__ win,
    const unsigned short* __restrict__ Bpack,
    float* __restrict__ out_mem, float* __restrict__ out_lu, int E, int N)
{
    __shared__ unsigned short sA[2 * ABUF];      // 122880 B double buffer
    __shared__ int   s_other[TPB * MB];
    __shared__ int   s_j[TPB * MB];
    __shared__ int   s_has[TPB * MB];
    __shared__ float s_dt[TPB * MB];

    const int tid = threadIdx.x;
    const int ntiles    = (N + MB - 1) / MB;
    const int tile_base = blockIdx.x * TPB;
    const int ntl       = min(TPB, ntiles - tile_base);
    if (ntl <= 0) return;

    // --- decode all tiles' winners (+ out_lu) ---
    for (int it0 = tid; it0 < ntl * MB; it0 += BLK) {
        const int lt = it0 / MB, nl = it0 - lt * MB;
        const int node = (tile_base + lt) * MB + nl;
        int has = 0, j = 0, other = 0; float dt = 0.f;
        if (node < N) {
            int lu = last_update[node];
            int w  = win[node];
            int te = lu;
            if (w >= 0) {
                has = 1;
                int e = (w < E) ? w : (w - E);
                j = e;
                other = (w < E) ? dst[e] : src[e];
                te = t[e];
                dt = (float)(te - lu);
            }
            out_lu[node] = (float)(te > lu ? te : lu);
        }
        s_j[it0] = j; s_other[it0] = other; s_has[it0] = has; s_dt[it0] = dt;
    }
    __syncthreads();

    const int wv    = tid >> 6;          // 0..6
    const int lane  = tid & 63;
    const int lrow  = lane & 15;
    const int lhi   = lane >> 4;
    const int slotl = lhi * 16 + (lrow ^ (lhi << 2));

    float4 va[8], vb[8];

    // --- prologue: stage tile 0 into buf0 ---
    issue_loads(0, tid, tile_base * MB, N, s_j, s_other, s_has, memory, raw_msg, va, vb);
    cvt_write(0, tid, sA, s_has, s_dt, te_w, te_b, va, vb);
    pipe_barrier();

    for (int i = 0; i < ntl; ++i) {
        unsigned short* bufc = sA + (size_t)(i & 1) * ABUF;
        unsigned short* bufn = sA + (size_t)((i + 1) & 1) * ABUF;

        // issue next tile's loads FIRST; they fly during the MFMA below
        if (i + 1 < ntl)
            issue_loads(i + 1, tid, (tile_base + i + 1) * MB, N, s_j, s_other, s_has,
                        memory, raw_msg, va, vb);
        __builtin_amdgcn_sched_barrier(0);

        // --- MFMA on current buffer ---
        f32x4 ar[GRPS], az[GRPS], an[GRPS], ah[GRPS];
#pragma unroll
        for (int m = 0; m < GRPS; ++m) { ar[m] = (f32x4)0.f; az[m] = (f32x4)0.f; an[m] = (f32x4)0.f; ah[m] = (f32x4)0.f; }

        __builtin_amdgcn_s_setprio(1);
#pragma unroll
        for (int ks = 0; ks < NKS; ++ks) {
            short8 a0 = *(const short8*)&bufc[((0 * NKS + ks) * SLOTS + slotl) * 8];
            short8 a1 = *(const short8*)&bufc[((1 * NKS + ks) * SLOTS + slotl) * 8];
            short8 a2 = *(const short8*)&bufc[((2 * NKS + ks) * SLOTS + slotl) * 8];
            short8 br = *(const short8*)&Bpack[(((size_t)(     wv) * NKS + ks) * 64 + lane) * 8];
            short8 bz = *(const short8*)&Bpack[(((size_t)( 7 + wv) * NKS + ks) * 64 + lane) * 8];
            short8 bn = (ks < 16)
                      ? *(const short8*)&Bpack[(((size_t)(14 + wv) * NKS + ks) * 64 + lane) * 8]
                      : *(const short8*)&Bpack[(((size_t)(21 + wv) * NKS + ks) * 64 + lane) * 8];
            ar[0] = mfma16(a0, br, ar[0]);  ar[1] = mfma16(a1, br, ar[1]);  ar[2] = mfma16(a2, br, ar[2]);
            az[0] = mfma16(a0, bz, az[0]);  az[1] = mfma16(a1, bz, az[1]);  az[2] = mfma16(a2, bz, az[2]);
            if (ks < 16) { an[0] = mfma16(a0, bn, an[0]);  an[1] = mfma16(a1, bn, an[1]);  an[2] = mfma16(a2, bn, an[2]); }
            else         { ah[0] = mfma16(a0, bn, ah[0]);  ah[1] = mfma16(a1, bn, ah[1]);  ah[2] = mfma16(a2, bn, ah[2]); }
        }
        __builtin_amdgcn_s_setprio(0);

        // --- epilogue: gates + store (h from current buffer's hh section) ---
        {
            const int node0 = (tile_base + i) * MB;
            const int c = wv * 16 + lrow;
            if (c < 100) {
                const float br_ = b_ih[c]       + b_hh[c];
                const float bz_ = b_ih[c + 100] + b_hh[c + 100];
                const float bin = b_ih[c + 200];
                const float bhn = b_hh[c + 200];
                const int ksh = 16 + (c >> 5);
                const int sbh = (c >> 3) & 3;
                const int ceh = c & 7;
#pragma unroll
                for (int m = 0; m < GRPS; ++m) {
#pragma unroll
                    for (int r = 0; r < 4; ++r) {
                        const int node = node0 + m * 16 + lhi * 4 + r;
                        if (node < N) {
                            const int rw   = lhi * 4 + r;
                            const int slot = sbh * 16 + (rw ^ (sbh << 2));
                            const float h  = bf2f(bufc[((m * NKS + ksh) * SLOTS + slot) * 8 + ceh]);
                            const float rg = 1.f / (1.f + __expf(-(ar[m][r] + br_)));
                            const float zg = 1.f / (1.f + __expf(-(az[m][r] + bz_)));
                            const float xn = an[m][r] + bin + rg * (ah[m][r] + bhn);
                            const float ex = __expf(2.f * fabsf(xn));
                            const float th = copysignf(1.f - 2.f / (ex + 1.f), xn);
                            out_mem[(size_t)node * H + c] = (1.f - zg) * th + zg * h;
                        }
                    }
                }
            }
        }

        // --- write next tile into the other buffer, then one barrier per tile ---
        if (i + 1 < ntl)
            cvt_write(i + 1, tid, bufn, s_has, s_dt, te_w, te_b, va, vb);
        pipe_barrier();
    }
}

extern "C" void kernel_launch(void* const* d_in, const int* in_sizes, int n_in,
                              void* d_out, int out_size, void* d_ws, size_t ws_size,
                              hipStream_t stream)
{
    const int*   src         = (const int*)d_in[0];
    const int*   dst         = (const int*)d_in[1];
    const int*   t           = (const int*)d_in[2];
    const float* raw_msg     = (const float*)d_in[3];
    const float* memory      = (const float*)d_in[4];
    const int*   last_update = (const int*)d_in[5];
    const float* te_w        = (const float*)d_in[6];
    const float* te_b        = (const float*)d_in[7];
    const float* w_ih        = (const float*)d_in[8];
    const float* w_hh        = (const float*)d_in[9];
    const float* b_ih        = (const float*)d_in[10];
    const float* b_hh        = (const float*)d_in[11];

    const int E = in_sizes[0];   // 100000
    const int N = in_sizes[5];   // 200000

    float* out    = (float*)d_out;
    float* out_lu = out + (size_t)N * H;

    int* maxt = (int*)d_ws;
    int* win  = maxt + N;
    unsigned short* Bpack = (unsigned short*)(win + N);

    const int ntiles = (N + MB - 1) / MB;
    const int nblk   = (ntiles + TPB - 1) / TPB;

    k_init<<<(N + 255) / 256, 256, 0, stream>>>(maxt, win, N);
    k_prep<<<(BPK_N + 255) / 256, 256, 0, stream>>>(w_ih, w_hh, Bpack);
    k_maxt<<<(E + 255) / 256, 256, 0, stream>>>(src, dst, t, maxt, E);
    k_win <<<(E + 255) / 256, 256, 0, stream>>>(src, dst, t, maxt, win, E);
    k_gru <<<nblk, BLK, 0, stream>>>(src, dst, t, raw_msg, memory, last_update,
                                     te_w, te_b, b_ih, b_hh, win, Bpack,
                                     out, out_lu, E, N);
}

// Round 9
// 480.112 us; speedup vs baseline: 1.4859x; 1.4859x over previous
//
#include <hip/hip_runtime.h>
#include <math.h>

typedef __attribute__((ext_vector_type(8))) short  short8;
typedef __attribute__((ext_vector_type(4))) float  f32x4;

// Problem constants: N=200000, E=100000, H=100, R=172, T=100
static constexpr int H     = 100;
static constexpr int RD    = 172;
static constexpr int WK    = 472;            // w_ih K
// Padded K layout (8-col chunks), chunk index c:
//  c [0,13)   mem[node]  (msg part; has-masked copy of hh chunks)
//  c [13,26)  mem[other]
//  c [26,48)  raw_msg
//  c [48,64)  time-enc
//  c [64,80)  mem[node]  (hh part, always present)
static constexpr int NKS   = 20;             // K-steps of 32 (KTOT=640)
static constexpr int MB    = 48;             // nodes per tile
static constexpr int GRPS  = 3;              // 16-row groups
static constexpr int BLK   = 448;            // 7 waves
static constexpr int SLOTS = 64;             // 16B slots per (grp,ks) tile
static constexpr int TPB   = 6;              // tiles per block (pipelined)
static constexpr int ABUF  = GRPS * NKS * SLOTS * 8;   // ushorts per A buffer (30720)
// B tiles: [0,7) r (w_hh folded), [7,14) z (folded), [14,21) n-ih (ks<16), [21,28) n-hh (ks>=16)
static constexpr int NTT   = 28;
static constexpr int BPK_N = NTT * NKS * 64 * 8;   // 286720 bf16

__device__ inline unsigned short f2bf(float x) {
    union { float f; unsigned u; } v; v.f = x;
    return (unsigned short)((v.u + 0x7FFFu + ((v.u >> 16) & 1u)) >> 16);
}
__device__ inline float bf2f(unsigned short b) {
    union { unsigned u; float f; } v; v.u = ((unsigned)b) << 16;
    return v.f;
}
__device__ inline unsigned pkbf(float a, float b) {
    unsigned r;
    asm("v_cvt_pk_bf16_f32 %0, %1, %2" : "=v"(r) : "v"(a), "v"(b));
    return r;
}
__device__ inline f32x4 mfma16(short8 a, short8 b, f32x4 c) {
    return __builtin_amdgcn_mfma_f32_16x16x32_bf16(a, b, c, 0, 0, 0);
}
__device__ inline float4 ld4g(const float* base, int lc, int limit) {
    if (lc + 4 <= limit) return *(const float4*)(base + lc);
    return make_float4(0.f, 0.f, 0.f, 0.f);
}
__device__ inline void pipe_barrier() {
    __builtin_amdgcn_sched_barrier(0);
    asm volatile("s_waitcnt lgkmcnt(0)" ::: "memory");
    __builtin_amdgcn_sched_barrier(0);
    __builtin_amdgcn_s_barrier();
    __builtin_amdgcn_sched_barrier(0);
}

// ---------------- aggregation kernels ----------------
__global__ __launch_bounds__(256) void k_init(int* __restrict__ maxt, int* __restrict__ win, int N) {
    int i = blockIdx.x * blockDim.x + threadIdx.x;
    if (i < N) { maxt[i] = (int)0x80000000; win[i] = -1; }
}

__global__ __launch_bounds__(256) void k_maxt(const int* __restrict__ src, const int* __restrict__ dst,
                                              const int* __restrict__ t, int* __restrict__ maxt, int E) {
    int j = blockIdx.x * blockDim.x + threadIdx.x;
    if (j < E) {
        int tj = t[j];
        atomicMax(&maxt[src[j]], tj);
        atomicMax(&maxt[dst[j]], tj);
    }
}

__global__ __launch_bounds__(256) void k_win(const int* __restrict__ src, const int* __restrict__ dst,
                                             const int* __restrict__ t, const int* __restrict__ maxt,
                                             int* __restrict__ win, int E) {
    int j = blockIdx.x * blockDim.x + threadIdx.x;
    if (j < E) {
        int tj = t[j];
        int s = src[j], d = dst[j];
        if (maxt[s] == tj) atomicMax(&win[s], j);
        if (maxt[d] == tj) atomicMax(&win[d], j + E);
    }
}

// ---------------- weight prep ----------------
__global__ __launch_bounds__(256) void k_prep(const float* __restrict__ w_ih, const float* __restrict__ w_hh,
                                              unsigned short* __restrict__ B) {
    int idx = blockIdx.x * 256 + threadIdx.x;
    if (idx >= BPK_N) return;
    int jj   = idx & 7;
    int lane = (idx >> 3) & 63;
    int rest = idx >> 9;          // tile*NKS + ks
    int ks   = rest % NKS;
    int tile = rest / NKS;
    int kk   = ks * 32 + ((lane >> 4) << 3) + jj;
    float v = 0.f;
    if (tile < 21) {
        int gate = tile / 7;
        int tcol = (tile % 7) * 16 + (lane & 15);
        if (tcol < 100) {
            if (kk < 512) {
                int col = -1;
                if (kk < 100)                   col = kk;          // mem[node]
                else if (kk >= 104 && kk < 204) col = kk - 4;      // mem[other]
                else if (kk >= 208 && kk < 380) col = kk - 8;      // raw
                else if (kk >= 384 && kk < 484) col = kk - 12;     // tenc
                if (col >= 0) v = w_ih[(gate * 100 + tcol) * WK + col];
            } else {
                int khh = kk - 512;
                if (gate < 2 && khh < 100)                          // fold w_hh for r,z
                    v = w_hh[(gate * 100 + tcol) * H + khh];
            }
        }
    } else {
        int tcol = (tile - 21) * 16 + (lane & 15);
        int khh  = kk - 512;
        if (tcol < 100 && khh >= 0 && khh < 100)
            v = w_hh[(200 + tcol) * H + khh];
    }
    B[idx] = f2bf(v);
}

// ---------------- staging helpers (half-tile granularity, 4 chunks/thread) ----------------
template<int HI>
__device__ inline void issue_half(int lt, int tid, int node_base, int N,
                                  const int* s_j, const int* s_other, const int* s_has,
                                  const float* memory, const float* raw_msg,
                                  float4 (&va)[4], float4 (&vb)[4])
{
    if (tid >= 432) return;
    const int nl = tid % 48, c0 = tid / 48;
    const int node  = node_base + nl;
    const bool valid = node < N;
    const int has   = s_has[lt * MB + nl];
    const float* memN = memory + (size_t)node * H;
    const float* memO = memory + (size_t)s_other[lt * MB + nl] * H;
    const float* rawJ = raw_msg + (size_t)s_j[lt * MB + nl] * RD;
#pragma unroll
    for (int u = 0; u < 4; ++u) {
        const int cc = c0 + (HI * 4 + u) * 9;
        va[u] = make_float4(0.f, 0.f, 0.f, 0.f); vb[u] = va[u];
        if (cc < 67) {
            const int c = cc + 13, kb = c * 8;
            if (c < 26)      { if (has)  { va[u] = ld4g(memO, kb - 104, 100); vb[u] = ld4g(memO, kb - 100, 100); } }
            else if (c < 48) { if (has)  { va[u] = ld4g(rawJ, kb - 208, RD ); vb[u] = ld4g(rawJ, kb - 204, RD ); } }
            else if (c < 64) { /* tenc computed at write time */ }
            else             { if (valid){ va[u] = ld4g(memN, kb - 512, 100); vb[u] = ld4g(memN, kb - 508, 100); } }
        }
    }
}

template<int HI>
__device__ inline void cvt_half(int lt, int tid, unsigned short* __restrict__ buf,
                                const int* s_has, const float* s_dt,
                                const float* te_w, const float* te_b,
                                float4 (&va)[4], float4 (&vb)[4])
{
    if (tid >= 432) return;
    const int nl = tid % 48, c0 = tid / 48;
    const int has = s_has[lt * MB + nl];
    const float dt = s_dt[lt * MB + nl];
    const int grp = nl >> 4, row = nl & 15;
#pragma unroll
    for (int u = 0; u < 4; ++u) {
        const int cc = c0 + (HI * 4 + u) * 9;
        if (cc >= 67) continue;
        const int c = cc + 13;
        if (c >= 48 && c < 64) {                  // tenc: pure VALU, no global loads
            if (has) {
                const int lc = c * 8 - 384;
                float vv[8];
#pragma unroll
                for (int q = 0; q < 8; ++q) {
                    int col = lc + q;
                    vv[q] = (col < 100) ? __cosf(fmaf(dt, te_w[col], te_b[col])) : 0.f;
                }
                va[u] = make_float4(vv[0], vv[1], vv[2], vv[3]);
                vb[u] = make_float4(vv[4], vv[5], vv[6], vv[7]);
            }
        }
        int4 sv;
        sv.x = (int)pkbf(va[u].x, va[u].y);
        sv.y = (int)pkbf(va[u].z, va[u].w);
        sv.z = (int)pkbf(vb[u].x, vb[u].y);
        sv.w = (int)pkbf(vb[u].z, vb[u].w);
        {
            const int ks = c >> 2, sub = c & 3;
            const int slot = sub * 16 + (row ^ (sub << 2));
            *(int4*)&buf[((grp * NKS + ks) * SLOTS + slot) * 8] = sv;
        }
        if (c >= 64 && c < 77) {                  // msg copy of mem[node], has-masked
            int4 sm_;
            sm_.x = has ? sv.x : 0; sm_.y = has ? sv.y : 0;
            sm_.z = has ? sv.z : 0; sm_.w = has ? sv.w : 0;
            const int cm = c - 64;
            const int ks = cm >> 2, sub = cm & 3;
            const int slot = sub * 16 + (row ^ (sub << 2));
            *(int4*)&buf[((grp * NKS + ks) * SLOTS + slot) * 8] = sm_;
        }
    }
}

// ---------------- fused GRU: pipelined bf16-MFMA over TPB tiles ----------------
__global__ __launch_bounds__(BLK, 1) void k_gru(
    const int* __restrict__ src, const int* __restrict__ dst, const int* __restrict__ t,
    const float* __restrict__ raw_msg, const float* __restrict__ memory,
    const int* __restrict__ last_update, const float* __restrict__ te_w,
    const float* __restrict__ te_b, const float* __restrict__ b_ih,
    const float* __restrict__ b_hh, const int* __restrict__ win,
    const unsigned short* __restrict__ Bpack,
    float* __restrict__ out_mem, float* __restrict__ out_lu, int E, int N)
{
    __shared__ unsigned short sA[2 * ABUF];      // 122880 B double buffer
    __shared__ int   s_other[TPB * MB];
    __shared__ int   s_j[TPB * MB];
    __shared__ int   s_has[TPB * MB];
    __shared__ float s_dt[TPB * MB];

    const int tid = threadIdx.x;
    const int ntiles    = (N + MB - 1) / MB;
    const int tile_base = blockIdx.x * TPB;
    const int ntl       = min(TPB, ntiles - tile_base);
    if (ntl <= 0) return;

    // --- decode all tiles' winners (+ out_lu) ---
    for (int it0 = tid; it0 < ntl * MB; it0 += BLK) {
        const int lt = it0 / MB, nl = it0 - lt * MB;
        const int node = (tile_base + lt) * MB + nl;
        int has = 0, j = 0, other = 0; float dt = 0.f;
        if (node < N) {
            int lu = last_update[node];
            int w  = win[node];
            int te = lu;
            if (w >= 0) {
                has = 1;
                int e = (w < E) ? w : (w - E);
                j = e;
                other = (w < E) ? dst[e] : src[e];
                te = t[e];
                dt = (float)(te - lu);
            }
            out_lu[node] = (float)(te > lu ? te : lu);
        }
        s_j[it0] = j; s_other[it0] = other; s_has[it0] = has; s_dt[it0] = dt;
    }
    __syncthreads();

    const int wv    = tid >> 6;          // 0..6
    const int lane  = tid & 63;
    const int lrow  = lane & 15;
    const int lhi   = lane >> 4;
    const int slotl = lhi * 16 + (lrow ^ (lhi << 2));

    float4 va[4], vb[4];

    // --- prologue: stage tile 0 into buf0 (two halves) ---
    issue_half<0>(0, tid, tile_base * MB, N, s_j, s_other, s_has, memory, raw_msg, va, vb);
    cvt_half<0>(0, tid, sA, s_has, s_dt, te_w, te_b, va, vb);
    issue_half<1>(0, tid, tile_base * MB, N, s_j, s_other, s_has, memory, raw_msg, va, vb);
    cvt_half<1>(0, tid, sA, s_has, s_dt, te_w, te_b, va, vb);
    pipe_barrier();

    for (int i = 0; i < ntl; ++i) {
        unsigned short* bufc = sA + (size_t)(i & 1) * ABUF;
        unsigned short* bufn = sA + (size_t)((i + 1) & 1) * ABUF;
        const bool more = (i + 1 < ntl);
        const int  nb   = (tile_base + i + 1) * MB;

        // issue half0 of next tile; loads fly during first MFMA half
        if (more)
            issue_half<0>(i + 1, tid, nb, N, s_j, s_other, s_has, memory, raw_msg, va, vb);
        __builtin_amdgcn_sched_barrier(0);

        f32x4 ar[GRPS], az[GRPS], an[GRPS], ah[GRPS];
#pragma unroll
        for (int m = 0; m < GRPS; ++m) { ar[m] = (f32x4)0.f; az[m] = (f32x4)0.f; an[m] = (f32x4)0.f; ah[m] = (f32x4)0.f; }

        // --- MFMA half 1: ks 0..9 ---
        __builtin_amdgcn_s_setprio(1);
#pragma unroll
        for (int ks = 0; ks < 10; ++ks) {
            short8 a0 = *(const short8*)&bufc[((0 * NKS + ks) * SLOTS + slotl) * 8];
            short8 a1 = *(const short8*)&bufc[((1 * NKS + ks) * SLOTS + slotl) * 8];
            short8 a2 = *(const short8*)&bufc[((2 * NKS + ks) * SLOTS + slotl) * 8];
            short8 br = *(const short8*)&Bpack[(((size_t)(     wv) * NKS + ks) * 64 + lane) * 8];
            short8 bz = *(const short8*)&Bpack[(((size_t)( 7 + wv) * NKS + ks) * 64 + lane) * 8];
            short8 bn = *(const short8*)&Bpack[(((size_t)(14 + wv) * NKS + ks) * 64 + lane) * 8];
            ar[0] = mfma16(a0, br, ar[0]);  ar[1] = mfma16(a1, br, ar[1]);  ar[2] = mfma16(a2, br, ar[2]);
            az[0] = mfma16(a0, bz, az[0]);  az[1] = mfma16(a1, bz, az[1]);  az[2] = mfma16(a2, bz, az[2]);
            an[0] = mfma16(a0, bn, an[0]);  an[1] = mfma16(a1, bn, an[1]);  an[2] = mfma16(a2, bn, an[2]);
        }
        __builtin_amdgcn_s_setprio(0);
        __builtin_amdgcn_sched_barrier(0);

        // write half0 of next tile (other buffer), then issue half1
        if (more) {
            cvt_half<0>(i + 1, tid, bufn, s_has, s_dt, te_w, te_b, va, vb);
            issue_half<1>(i + 1, tid, nb, N, s_j, s_other, s_has, memory, raw_msg, va, vb);
        }
        __builtin_amdgcn_sched_barrier(0);

        // --- MFMA half 2: ks 10..19 ---
        __builtin_amdgcn_s_setprio(1);
#pragma unroll
        for (int ks = 10; ks < NKS; ++ks) {
            short8 a0 = *(const short8*)&bufc[((0 * NKS + ks) * SLOTS + slotl) * 8];
            short8 a1 = *(const short8*)&bufc[((1 * NKS + ks) * SLOTS + slotl) * 8];
            short8 a2 = *(const short8*)&bufc[((2 * NKS + ks) * SLOTS + slotl) * 8];
            short8 br = *(const short8*)&Bpack[(((size_t)(     wv) * NKS + ks) * 64 + lane) * 8];
            short8 bz = *(const short8*)&Bpack[(((size_t)( 7 + wv) * NKS + ks) * 64 + lane) * 8];
            short8 bn = (ks < 16)
                      ? *(const short8*)&Bpack[(((size_t)(14 + wv) * NKS + ks) * 64 + lane) * 8]
                      : *(const short8*)&Bpack[(((size_t)(21 + wv) * NKS + ks) * 64 + lane) * 8];
            ar[0] = mfma16(a0, br, ar[0]);  ar[1] = mfma16(a1, br, ar[1]);  ar[2] = mfma16(a2, br, ar[2]);
            az[0] = mfma16(a0, bz, az[0]);  az[1] = mfma16(a1, bz, az[1]);  az[2] = mfma16(a2, bz, az[2]);
            if (ks < 16) { an[0] = mfma16(a0, bn, an[0]);  an[1] = mfma16(a1, bn, an[1]);  an[2] = mfma16(a2, bn, an[2]); }
            else         { ah[0] = mfma16(a0, bn, ah[0]);  ah[1] = mfma16(a1, bn, ah[1]);  ah[2] = mfma16(a2, bn, ah[2]); }
        }
        __builtin_amdgcn_s_setprio(0);

        // --- epilogue: gates + store (h from current buffer's hh section) ---
        {
            const int node0 = (tile_base + i) * MB;
            const int c = wv * 16 + lrow;
            if (c < 100) {
                const float br_ = b_ih[c]       + b_hh[c];
                const float bz_ = b_ih[c + 100] + b_hh[c + 100];
                const float bin = b_ih[c + 200];
                const float bhn = b_hh[c + 200];
                const int ksh = 16 + (c >> 5);
                const int sbh = (c >> 3) & 3;
                const int ceh = c & 7;
#pragma unroll
                for (int m = 0; m < GRPS; ++m) {
#pragma unroll
                    for (int r = 0; r < 4; ++r) {
                        const int node = node0 + m * 16 + lhi * 4 + r;
                        if (node < N) {
                            const int rw   = lhi * 4 + r;
                            const int slot = sbh * 16 + (rw ^ (sbh << 2));
                            const float h  = bf2f(bufc[((m * NKS + ksh) * SLOTS + slot) * 8 + ceh]);
                            const float rg = 1.f / (1.f + __expf(-(ar[m][r] + br_)));
                            const float zg = 1.f / (1.f + __expf(-(az[m][r] + bz_)));
                            const float xn = an[m][r] + bin + rg * (ah[m][r] + bhn);
                            const float ex = __expf(2.f * fabsf(xn));
                            const float th = copysignf(1.f - 2.f / (ex + 1.f), xn);
                            out_mem[(size_t)node * H + c] = (1.f - zg) * th + zg * h;
                        }
                    }
                }
            }
        }

        // write half1 of next tile, then one barrier per tile
        if (more)
            cvt_half<1>(i + 1, tid, bufn, s_has, s_dt, te_w, te_b, va, vb);
        pipe_barrier();
    }
}

extern "C" void kernel_launch(void* const* d_in, const int* in_sizes, int n_in,
                              void* d_out, int out_size, void* d_ws, size_t ws_size,
                              hipStream_t stream)
{
    const int*   src         = (const int*)d_in[0];
    const int*   dst         = (const int*)d_in[1];
    const int*   t           = (const int*)d_in[2];
    const float* raw_msg     = (const float*)d_in[3];
    const float* memory      = (const float*)d_in[4];
    const int*   last_update = (const int*)d_in[5];
    const float* te_w        = (const float*)d_in[6];
    const float* te_b        = (const float*)d_in[7];
    const float* w_ih        = (const float*)d_in[8];
    const float* w_hh        = (const float*)d_in[9];
    const float* b_ih        = (const float*)d_in[10];
    const float* b_hh        = (const float*)d_in[11];

    const int E = in_sizes[0];   // 100000
    const int N = in_sizes[5];   // 200000

    float* out    = (float*)d_out;
    float* out_lu = out + (size_t)N * H;

    int* maxt = (int*)d_ws;
    int* win  = maxt + N;
    unsigned short* Bpack = (unsigned short*)(win + N);

    const int ntiles = (N + MB - 1) / MB;
    const int nblk   = (ntiles + TPB - 1) / TPB;

    k_init<<<(N + 255) / 256, 256, 0, stream>>>(maxt, win, N);
    k_prep<<<(BPK_N + 255) / 256, 256, 0, stream>>>(w_ih, w_hh, Bpack);
    k_maxt<<<(E + 255) / 256, 256, 0, stream>>>(src, dst, t, maxt, E);
    k_win <<<(E + 255) / 256, 256, 0, stream>>>(src, dst, t, maxt, win, E);
    k_gru <<<nblk, BLK, 0, stream>>>(src, dst, t, raw_msg, memory, last_update,
                                     te_w, te_b, b_ih, b_hh, win, Bpack,
                                     out, out_lu, E, N);
}

// Round 10
// 385.260 us; speedup vs baseline: 1.8517x; 1.2462x over previous
//
#include <hip/hip_runtime.h>
#include <math.h>

typedef __attribute__((ext_vector_type(8))) short  short8;
typedef __attribute__((ext_vector_type(4))) float  f32x4;

// Problem constants: N=200000, E=100000, H=100, R=172, T=100
static constexpr int H     = 100;
static constexpr int RD    = 172;
static constexpr int WK    = 472;            // w_ih K
// Padded K layout, element k:
//  [0,104)   mem[node]  (msg part, masked by has)
//  [104,208) mem[other]
//  [208,384) raw_msg (172+4)
//  [384,512) time-enc (100+28)
//  [512,640) mem[node] (hh part, always present)
static constexpr int NKS   = 20;             // K-steps of 32 (KTOT=640)
static constexpr int MB    = 48;             // nodes per block
static constexpr int GRPS  = 3;              // 16-row groups
static constexpr int BLK   = 448;            // 7 waves, wave wv owns cols wv*16..+15 of all gates
// B tiles: [0,7) r (w_hh folded), [7,14) z (folded), [14,21) n-ih (ks<16), [21,28) n-hh (ks>=16)
static constexpr int NTT   = 28;
static constexpr int BPK_N = NTT * NKS * 64 * 8;   // 286720 bf16
static constexpr int ZBF   = 256;            // zero-buffer floats

__device__ inline unsigned short f2bf(float x) {
    union { float f; unsigned u; } v; v.f = x;
    return (unsigned short)((v.u + 0x7FFFu + ((v.u >> 16) & 1u)) >> 16);
}
__device__ inline unsigned pkbf(float a, float b) {
    unsigned r;
    asm("v_cvt_pk_bf16_f32 %0, %1, %2" : "=v"(r) : "v"(a), "v"(b));
    return r;
}
__device__ inline f32x4 mfma16(short8 a, short8 b, f32x4 c) {
    return __builtin_amdgcn_mfma_f32_16x16x32_bf16(a, b, c, 0, 0, 0);
}
__device__ inline float4 ld4g(const float* base, int lc, int limit) {
    if (lc + 4 <= limit) return *(const float4*)(base + lc);
    return make_float4(0.f, 0.f, 0.f, 0.f);
}

// ---------------- aggregation kernels ----------------
__global__ __launch_bounds__(256) void k_init(int* __restrict__ maxt, int* __restrict__ win,
                                              float* __restrict__ zbuf, int N) {
    int i = blockIdx.x * blockDim.x + threadIdx.x;
    if (i < N) { maxt[i] = (int)0x80000000; win[i] = -1; }
    if (i < ZBF) zbuf[i] = 0.f;
}

__global__ __launch_bounds__(256) void k_maxt(const int* __restrict__ src, const int* __restrict__ dst,
                                              const int* __restrict__ t, int* __restrict__ maxt, int E) {
    int j = blockIdx.x * blockDim.x + threadIdx.x;
    if (j < E) {
        int tj = t[j];
        atomicMax(&maxt[src[j]], tj);
        atomicMax(&maxt[dst[j]], tj);
    }
}

__global__ __launch_bounds__(256) void k_win(const int* __restrict__ src, const int* __restrict__ dst,
                                             const int* __restrict__ t, const int* __restrict__ maxt,
                                             int* __restrict__ win, int E) {
    int j = blockIdx.x * blockDim.x + threadIdx.x;
    if (j < E) {
        int tj = t[j];
        int s = src[j], d = dst[j];
        if (maxt[s] == tj) atomicMax(&win[s], j);
        if (maxt[d] == tj) atomicMax(&win[d], j + E);
    }
}

__global__ __launch_bounds__(256) void k_lu(const int* __restrict__ last_update, const int* __restrict__ maxt,
                                            float* __restrict__ out_lu, int N) {
    int i = blockIdx.x * blockDim.x + threadIdx.x;
    if (i < N) {
        int m = maxt[i], lu = last_update[i];
        out_lu[i] = (float)(m > lu ? m : lu);
    }
}

// ---------------- weight prep (unchanged layout) ----------------
__global__ __launch_bounds__(256) void k_prep(const float* __restrict__ w_ih, const float* __restrict__ w_hh,
                                              unsigned short* __restrict__ B) {
    int idx = blockIdx.x * 256 + threadIdx.x;
    if (idx >= BPK_N) return;
    int jj   = idx & 7;
    int lane = (idx >> 3) & 63;
    int rest = idx >> 9;          // tile*NKS + ks
    int ks   = rest % NKS;
    int tile = rest / NKS;
    int kk   = ks * 32 + ((lane >> 4) << 3) + jj;
    float v = 0.f;
    if (tile < 21) {
        int gate = tile / 7;
        int tcol = (tile % 7) * 16 + (lane & 15);
        if (tcol < 100) {
            if (kk < 512) {
                int col = -1;
                if (kk < 100)                   col = kk;          // mem[node]
                else if (kk >= 104 && kk < 204) col = kk - 4;      // mem[other]
                else if (kk >= 208 && kk < 380) col = kk - 8;      // raw
                else if (kk >= 384 && kk < 484) col = kk - 12;     // tenc
                if (col >= 0) v = w_ih[(gate * 100 + tcol) * WK + col];
            } else {
                int khh = kk - 512;
                if (gate < 2 && khh < 100)                          // fold w_hh for r,z
                    v = w_hh[(gate * 100 + tcol) * H + khh];
            }
        }
    } else {
        int tcol = (tile - 21) * 16 + (lane & 15);
        int khh  = kk - 512;
        if (tcol < 100 && khh >= 0 && khh < 100)
            v = w_hh[(200 + tcol) * H + khh];
    }
    B[idx] = f2bf(v);
}

// ---------------- fused GRU: LDS-free, per-wave global A-gather ----------------
__global__ __launch_bounds__(BLK) void k_gru(
    const int* __restrict__ src, const int* __restrict__ dst, const int* __restrict__ t,
    const float* __restrict__ raw_msg, const float* __restrict__ memory,
    const int* __restrict__ last_update, const float* __restrict__ te_w,
    const float* __restrict__ te_b, const float* __restrict__ b_ih,
    const float* __restrict__ b_hh, const int* __restrict__ win,
    const unsigned short* __restrict__ Bpack, const float* __restrict__ zbuf,
    float* __restrict__ out_mem, int E, int N)
{
    const int tid   = threadIdx.x;
    const int wv    = tid >> 6;          // 0..6 : col tile
    const int lane  = tid & 63;
    const int lrow  = lane & 15;
    const int q     = lane >> 4;         // k quarter: k0 = ks*32 + q*8
    const int node0 = blockIdx.x * MB;

    // --- per-lane metadata: this lane gathers A rows {node0 + g*16 + lrow} ---
    const float* pN[GRPS];   // mem[node] (hh region)
    const float* pM[GRPS];   // mem[node] (msg region, has-masked)
    const float* pO[GRPS];   // mem[other]
    const float* pR[GRPS];   // raw_msg[j]
    float hasf[GRPS], dtv[GRPS];
#pragma unroll
    for (int g = 0; g < GRPS; ++g) {
        const int node  = node0 + g * 16 + lrow;
        const bool valid = node < N;
        int w = valid ? win[node] : -1;
        const bool has = (w >= 0);
        int other = 0, jj = 0; float dt = 0.f;
        if (has) {
            const int lu = last_update[node];
            const int e  = (w < E) ? w : (w - E);
            jj    = e;
            other = (w < E) ? dst[e] : src[e];
            dt    = (float)(t[e] - lu);
        }
        pN[g]   = valid ? memory + (size_t)node * H : zbuf;
        pM[g]   = has ? memory + (size_t)node * H : zbuf;
        pO[g]   = has ? memory + (size_t)other * H : zbuf;
        pR[g]   = has ? raw_msg + (size_t)jj * RD : zbuf;
        hasf[g] = has ? 1.f : 0.f;
        dtv[g]  = dt;
    }

    f32x4 ar[GRPS], az[GRPS], an[GRPS], ah[GRPS];
#pragma unroll
    for (int m = 0; m < GRPS; ++m) { ar[m] = (f32x4)0.f; az[m] = (f32x4)0.f; an[m] = (f32x4)0.f; ah[m] = (f32x4)0.f; }

#pragma unroll
    for (int ks = 0; ks < NKS; ++ks) {
        short8 a[GRPS];
#pragma unroll
        for (int g = 0; g < GRPS; ++g) {
            const int k0 = ks * 32 + q * 8;
            float4 fa, fb;
            if (ks >= 12 && ks < 16) {               // tenc region [384,512)
                const int lc = k0 - 384;
                const float4 w0 = ld4g(te_w, lc, 100), w1 = ld4g(te_w, lc + 4, 100);
                const float4 c0 = ld4g(te_b, lc, 100), c1 = ld4g(te_b, lc + 4, 100);
                const float hf = hasf[g], dt = dtv[g];
                fa.x = hf * __cosf(fmaf(dt, w0.x, c0.x));
                fa.y = hf * __cosf(fmaf(dt, w0.y, c0.y));
                fa.z = hf * __cosf(fmaf(dt, w0.z, c0.z));
                fa.w = hf * __cosf(fmaf(dt, w0.w, c0.w));
                fb.x = hf * __cosf(fmaf(dt, w1.x, c1.x));
                fb.y = hf * __cosf(fmaf(dt, w1.y, c1.y));
                fb.z = hf * __cosf(fmaf(dt, w1.z, c1.z));
                fb.w = hf * __cosf(fmaf(dt, w1.w, c1.w));
            } else {
                const float* base; int off, lim;
                if (k0 < 104)      { base = pM[g]; off = k0;       lim = 100; }
                else if (k0 < 208) { base = pO[g]; off = k0 - 104; lim = 100; }
                else if (k0 < 384) { base = pR[g]; off = k0 - 208; lim = 172; }
                else               { base = pN[g]; off = k0 - 512; lim = 100; }
                fa = ld4g(base, off, lim);
                fb = ld4g(base, off + 4, lim);
            }
            union { int4 i; short8 s; } u;
            u.i.x = (int)pkbf(fa.x, fa.y);
            u.i.y = (int)pkbf(fa.z, fa.w);
            u.i.z = (int)pkbf(fb.x, fb.y);
            u.i.w = (int)pkbf(fb.z, fb.w);
            a[g] = u.s;
        }
        short8 br = *(const short8*)&Bpack[(((size_t)(     wv) * NKS + ks) * 64 + lane) * 8];
        short8 bz = *(const short8*)&Bpack[(((size_t)( 7 + wv) * NKS + ks) * 64 + lane) * 8];
        short8 bn = (ks < 16)
                  ? *(const short8*)&Bpack[(((size_t)(14 + wv) * NKS + ks) * 64 + lane) * 8]
                  : *(const short8*)&Bpack[(((size_t)(21 + wv) * NKS + ks) * 64 + lane) * 8];
        ar[0] = mfma16(a[0], br, ar[0]);  ar[1] = mfma16(a[1], br, ar[1]);  ar[2] = mfma16(a[2], br, ar[2]);
        az[0] = mfma16(a[0], bz, az[0]);  az[1] = mfma16(a[1], bz, az[1]);  az[2] = mfma16(a[2], bz, az[2]);
        if (ks < 16) { an[0] = mfma16(a[0], bn, an[0]);  an[1] = mfma16(a[1], bn, an[1]);  an[2] = mfma16(a[2], bn, an[2]); }
        else         { ah[0] = mfma16(a[0], bn, ah[0]);  ah[1] = mfma16(a[1], bn, ah[1]);  ah[2] = mfma16(a[2], bn, ah[2]); }
    }

    // --- in-register gates + store; h re-read from global (L2-hot) ---
    const int c = wv * 16 + lrow;
    if (c < 100) {
        const float br_ = b_ih[c]       + b_hh[c];
        const float bz_ = b_ih[c + 100] + b_hh[c + 100];
        const float bin = b_ih[c + 200];
        const float bhn = b_hh[c + 200];
#pragma unroll
        for (int m = 0; m < GRPS; ++m) {
#pragma unroll
            for (int r = 0; r < 4; ++r) {
                const int node = node0 + m * 16 + q * 4 + r;   // C/D: row=(lane>>4)*4+reg
                if (node < N) {
                    const float h  = memory[(size_t)node * H + c];
                    const float rg = 1.f / (1.f + __expf(-(ar[m][r] + br_)));
                    const float zg = 1.f / (1.f + __expf(-(az[m][r] + bz_)));
                    const float xn = an[m][r] + bin + rg * (ah[m][r] + bhn);
                    const float ex = __expf(2.f * fabsf(xn));
                    const float th = copysignf(1.f - 2.f / (ex + 1.f), xn);
                    out_mem[(size_t)node * H + c] = (1.f - zg) * th + zg * h;
                }
            }
        }
    }
}

extern "C" void kernel_launch(void* const* d_in, const int* in_sizes, int n_in,
                              void* d_out, int out_size, void* d_ws, size_t ws_size,
                              hipStream_t stream)
{
    const int*   src         = (const int*)d_in[0];
    const int*   dst         = (const int*)d_in[1];
    const int*   t           = (const int*)d_in[2];
    const float* raw_msg     = (const float*)d_in[3];
    const float* memory      = (const float*)d_in[4];
    const int*   last_update = (const int*)d_in[5];
    const float* te_w        = (const float*)d_in[6];
    const float* te_b        = (const float*)d_in[7];
    const float* w_ih        = (const float*)d_in[8];
    const float* w_hh        = (const float*)d_in[9];
    const float* b_ih        = (const float*)d_in[10];
    const float* b_hh        = (const float*)d_in[11];

    const int E = in_sizes[0];   // 100000
    const int N = in_sizes[5];   // 200000

    float* out    = (float*)d_out;
    float* out_lu = out + (size_t)N * H;

    int* maxt = (int*)d_ws;
    int* win  = maxt + N;
    unsigned short* Bpack = (unsigned short*)(win + N);
    float* zbuf = (float*)(Bpack + BPK_N);

    const int nblk = (N + MB - 1) / MB;

    k_init<<<(N + 255) / 256, 256, 0, stream>>>(maxt, win, zbuf, N);
    k_prep<<<(BPK_N + 255) / 256, 256, 0, stream>>>(w_ih, w_hh, Bpack);
    k_maxt<<<(E + 255) / 256, 256, 0, stream>>>(src, dst, t, maxt, E);
    k_win <<<(E + 255) / 256, 256, 0, stream>>>(src, dst, t, maxt, win, E);
    k_lu  <<<(N + 255) / 256, 256, 0, stream>>>(last_update, maxt, out_lu, N);
    k_gru <<<nblk, BLK, 0, stream>>>(src, dst, t, raw_msg, memory, last_update,
                                     te_w, te_b, b_ih, b_hh, win, Bpack, zbuf,
                                     out, E, N);
}

// Round 11
// 354.912 us; speedup vs baseline: 2.0101x; 1.0855x over previous
//
#include <hip/hip_runtime.h>
#include <math.h>

typedef __attribute__((ext_vector_type(8))) short  short8;
typedef __attribute__((ext_vector_type(4))) float  f32x4;

// Problem constants: N=200000, E=100000, H=100, R=172, T=100
static constexpr int H     = 100;
static constexpr int RD    = 172;
static constexpr int WK    = 472;
// Padded K layout (8-col chunks), chunk c:
//  [0,13) mem[node] (has-masked) | [13,26) mem[other] | [26,48) raw
//  [48,64) tenc | [64,80) mem[node] hh (always)
static constexpr int NKS   = 20;
static constexpr int CH    = 80;
static constexpr int MB    = 48;
static constexpr int GRPS  = 3;
static constexpr int BLK   = 448;
static constexpr int NTT   = 28;
static constexpr int BPK_N = NTT * NKS * 64 * 8;   // 286720 bf16
static constexpr int SEGMAX = 48000;               // nodes/segment (61.4 MB Apack, L3-resident)
static constexpr int SEGMIN = 8352;                // below this, fused fallback

__device__ inline unsigned short f2bf(float x) {
    union { float f; unsigned u; } v; v.f = x;
    return (unsigned short)((v.u + 0x7FFFu + ((v.u >> 16) & 1u)) >> 16);
}
__device__ inline float bf2f(unsigned short b) {
    union { unsigned u; float f; } v; v.u = ((unsigned)b) << 16;
    return v.f;
}
__device__ inline unsigned pkbf(float a, float b) {
    unsigned r;
    asm("v_cvt_pk_bf16_f32 %0, %1, %2" : "=v"(r) : "v"(a), "v"(b));
    return r;
}
__device__ inline f32x4 mfma16(short8 a, short8 b, f32x4 c) {
    return __builtin_amdgcn_mfma_f32_16x16x32_bf16(a, b, c, 0, 0, 0);
}
__device__ inline float4 ld4g(const float* base, int lc, int limit) {
    if (lc + 4 <= limit) return *(const float4*)(base + lc);
    return make_float4(0.f, 0.f, 0.f, 0.f);
}

// ---------------- aggregation ----------------
__global__ __launch_bounds__(256) void k_init(int* __restrict__ maxt, int* __restrict__ win, int N) {
    int i = blockIdx.x * blockDim.x + threadIdx.x;
    if (i < N) { maxt[i] = (int)0x80000000; win[i] = -1; }
}
__global__ __launch_bounds__(256) void k_maxt(const int* __restrict__ src, const int* __restrict__ dst,
                                              const int* __restrict__ t, int* __restrict__ maxt, int E) {
    int j = blockIdx.x * blockDim.x + threadIdx.x;
    if (j < E) {
        int tj = t[j];
        atomicMax(&maxt[src[j]], tj);
        atomicMax(&maxt[dst[j]], tj);
    }
}
__global__ __launch_bounds__(256) void k_win(const int* __restrict__ src, const int* __restrict__ dst,
                                             const int* __restrict__ t, const int* __restrict__ maxt,
                                             int* __restrict__ win, int E) {
    int j = blockIdx.x * blockDim.x + threadIdx.x;
    if (j < E) {
        int tj = t[j];
        int s = src[j], d = dst[j];
        if (maxt[s] == tj) atomicMax(&win[s], j);
        if (maxt[d] == tj) atomicMax(&win[d], j + E);
    }
}
// per-node meta {j, other, has, dt} + out_lu
__global__ __launch_bounds__(256) void k_meta(const int* __restrict__ src, const int* __restrict__ dst,
                                              const int* __restrict__ t, const int* __restrict__ last_update,
                                              const int* __restrict__ win, int4* __restrict__ meta,
                                              float* __restrict__ out_lu, int E, int N) {
    int i = blockIdx.x * blockDim.x + threadIdx.x;
    if (i >= N) return;
    int lu = last_update[i], w = win[i];
    int j = 0, other = 0, has = 0, te = lu; float dt = 0.f;
    if (w >= 0) {
        has = 1;
        int e = (w < E) ? w : (w - E);
        j = e;
        other = (w < E) ? dst[e] : src[e];
        te = t[e];
        dt = (float)(te - lu);
    }
    out_lu[i] = (float)(te > lu ? te : lu);
    int4 m; m.x = j; m.y = other; m.z = has; m.w = __float_as_int(dt);
    meta[i] = m;
}

// ---------------- weight prep ----------------
__global__ __launch_bounds__(256) void k_prep(const float* __restrict__ w_ih, const float* __restrict__ w_hh,
                                              unsigned short* __restrict__ B) {
    int idx = blockIdx.x * 256 + threadIdx.x;
    if (idx >= BPK_N) return;
    int jj   = idx & 7;
    int lane = (idx >> 3) & 63;
    int rest = idx >> 9;
    int ks   = rest % NKS;
    int tile = rest / NKS;
    int kk   = ks * 32 + ((lane >> 4) << 3) + jj;
    float v = 0.f;
    if (tile < 21) {
        int gate = tile / 7;
        int tcol = (tile % 7) * 16 + (lane & 15);
        if (tcol < 100) {
            if (kk < 512) {
                int col = -1;
                if (kk < 100)                   col = kk;
                else if (kk >= 104 && kk < 204) col = kk - 4;
                else if (kk >= 208 && kk < 380) col = kk - 8;
                else if (kk >= 384 && kk < 484) col = kk - 12;
                if (col >= 0) v = w_ih[(gate * 100 + tcol) * WK + col];
            } else {
                int khh = kk - 512;
                if (gate < 2 && khh < 100)
                    v = w_hh[(gate * 100 + tcol) * H + khh];
            }
        }
    } else {
        int tcol = (tile - 21) * 16 + (lane & 15);
        int khh  = kk - 512;
        if (tcol < 100 && khh >= 0 && khh < 100)
            v = w_hh[(200 + tcol) * H + khh];
    }
    B[idx] = f2bf(v);
}

// ---------------- k_gather: one thread per 16B fragment ----------------
// id = (t16_local*80 + c)*16 + row ; Apack[id*16B] (fragment order [t16][ks][q][row])
__global__ __launch_bounds__(256) void k_gather(
    const float* __restrict__ raw_msg, const float* __restrict__ memory,
    const float* __restrict__ te_w, const float* __restrict__ te_b,
    const int4* __restrict__ meta, unsigned short* __restrict__ Apack,
    int node_base, int nthreads, int N)
{
    int id = blockIdx.x * 256 + threadIdx.x;
    if (id >= nthreads) return;
    const int row = id & 15;
    const int cc  = id >> 4;
    const int c   = cc % CH;
    const int t16 = cc / CH;
    const int node = node_base + t16 * 16 + row;
    const bool vnode = node < N;

    float4 va = make_float4(0.f, 0.f, 0.f, 0.f), vb = va;
    int4 m = vnode ? meta[node] : make_int4(0, 0, 0, 0);
    const int has = m.z;
    const float dt = __int_as_float(m.w);

    if (c < 13) {
        if (has) { const float* p = memory + (size_t)node * H; int o = c * 8;
                   va = ld4g(p, o, 100); vb = ld4g(p, o + 4, 100); }
    } else if (c < 26) {
        if (has) { const float* p = memory + (size_t)m.y * H; int o = (c - 13) * 8;
                   va = ld4g(p, o, 100); vb = ld4g(p, o + 4, 100); }
    } else if (c < 48) {
        if (has) { const float* p = raw_msg + (size_t)m.x * RD; int o = (c - 26) * 8;
                   va = ld4g(p, o, RD); vb = ld4g(p, o + 4, RD); }
    } else if (c < 64) {
        if (has) {
            int o = (c - 48) * 8;
            float4 w0 = ld4g(te_w, o, 100), w1 = ld4g(te_w, o + 4, 100);
            float4 b0 = ld4g(te_b, o, 100), b1 = ld4g(te_b, o + 4, 100);
            va.x = __cosf(fmaf(dt, w0.x, b0.x)); va.y = __cosf(fmaf(dt, w0.y, b0.y));
            va.z = __cosf(fmaf(dt, w0.z, b0.z)); va.w = __cosf(fmaf(dt, w0.w, b0.w));
            vb.x = __cosf(fmaf(dt, w1.x, b1.x)); vb.y = __cosf(fmaf(dt, w1.y, b1.y));
            vb.z = __cosf(fmaf(dt, w1.z, b1.z)); vb.w = __cosf(fmaf(dt, w1.w, b1.w));
            // pad cols (>=100) give cos(0)=1 but multiply zero B weights -> harmless
        }
    } else {
        if (vnode) { const float* p = memory + (size_t)node * H; int o = (c - 64) * 8;
                     va = ld4g(p, o, 100); vb = ld4g(p, o + 4, 100); }
    }
    int4 sv;
    sv.x = (int)pkbf(va.x, va.y);
    sv.y = (int)pkbf(va.z, va.w);
    sv.z = (int)pkbf(vb.x, vb.y);
    sv.w = (int)pkbf(vb.z, vb.w);
    *(int4*)&Apack[(size_t)id * 8] = sv;
}

// ---------------- k_gemm: linear A -> LDS -> MFMA -> gates ----------------
__global__ __launch_bounds__(BLK) void k_gemm(
    const unsigned short* __restrict__ Apack, const unsigned short* __restrict__ Bpack,
    const float* __restrict__ b_ih, const float* __restrict__ b_hh,
    float* __restrict__ out_mem, int node_base, int N)
{
    __shared__ unsigned short sA[GRPS * NKS * 64 * 8];   // 61440 B, [g][ks][lane] 16B frags

    const int tid  = threadIdx.x;
    const int wv   = tid >> 6;
    const int lane = tid & 63;
    const int lrow = lane & 15;
    const int lhi  = lane >> 4;
    const int node0 = node_base + blockIdx.x * MB;
    const size_t ab = (size_t)blockIdx.x * 60 * 512;   // 60 tiles x 512 ushorts

    // stage: each wave covers tiles wv, wv+7, ... (static unroll, no dynamic indexing)
    int4 x[9];
#pragma unroll
    for (int i = 0; i < 9; ++i) {
        const int tl = wv + 7 * i;
        if (tl < 60) x[i] = *(const int4*)&Apack[ab + (size_t)tl * 512 + lane * 8];
    }
#pragma unroll
    for (int i = 0; i < 9; ++i) {
        const int tl = wv + 7 * i;
        if (tl < 60) *(int4*)&sA[tl * 512 + lane * 8] = x[i];
    }
    __syncthreads();

    f32x4 ar[GRPS], az[GRPS], an[GRPS], ah[GRPS];
#pragma unroll
    for (int m = 0; m < GRPS; ++m) { ar[m] = (f32x4)0.f; az[m] = (f32x4)0.f; an[m] = (f32x4)0.f; ah[m] = (f32x4)0.f; }

    __builtin_amdgcn_s_setprio(1);
#pragma unroll
    for (int ks = 0; ks < NKS; ++ks) {
        short8 a0 = *(const short8*)&sA[(0 * NKS + ks) * 512 + lane * 8];
        short8 a1 = *(const short8*)&sA[(1 * NKS + ks) * 512 + lane * 8];
        short8 a2 = *(const short8*)&sA[(2 * NKS + ks) * 512 + lane * 8];
        short8 br = *(const short8*)&Bpack[(((size_t)(     wv) * NKS + ks) * 64 + lane) * 8];
        short8 bz = *(const short8*)&Bpack[(((size_t)( 7 + wv) * NKS + ks) * 64 + lane) * 8];
        short8 bn = (ks < 16)
                  ? *(const short8*)&Bpack[(((size_t)(14 + wv) * NKS + ks) * 64 + lane) * 8]
                  : *(const short8*)&Bpack[(((size_t)(21 + wv) * NKS + ks) * 64 + lane) * 8];
        ar[0] = mfma16(a0, br, ar[0]);  ar[1] = mfma16(a1, br, ar[1]);  ar[2] = mfma16(a2, br, ar[2]);
        az[0] = mfma16(a0, bz, az[0]);  az[1] = mfma16(a1, bz, az[1]);  az[2] = mfma16(a2, bz, az[2]);
        if (ks < 16) { an[0] = mfma16(a0, bn, an[0]);  an[1] = mfma16(a1, bn, an[1]);  an[2] = mfma16(a2, bn, an[2]); }
        else         { ah[0] = mfma16(a0, bn, ah[0]);  ah[1] = mfma16(a1, bn, ah[1]);  ah[2] = mfma16(a2, bn, ah[2]); }
    }
    __builtin_amdgcn_s_setprio(0);

    const int c = wv * 16 + lrow;
    if (c < 100) {
        const float br_ = b_ih[c]       + b_hh[c];
        const float bz_ = b_ih[c + 100] + b_hh[c + 100];
        const float bin = b_ih[c + 200];
        const float bhn = b_hh[c + 200];
        const int ksh = 16 + (c >> 5);
        const int qh  = (c >> 3) & 3;
        const int e   = c & 7;
#pragma unroll
        for (int m = 0; m < GRPS; ++m) {
#pragma unroll
            for (int r = 0; r < 4; ++r) {
                const int node = node0 + m * 16 + lhi * 4 + r;
                if (node < N) {
                    const int rw = lhi * 4 + r;
                    const float h  = bf2f(sA[(m * NKS + ksh) * 512 + (qh * 16 + rw) * 8 + e]);
                    const float rg = 1.f / (1.f + __expf(-(ar[m][r] + br_)));
                    const float zg = 1.f / (1.f + __expf(-(az[m][r] + bz_)));
                    const float xn = an[m][r] + bin + rg * (ah[m][r] + bhn);
                    const float ex = __expf(2.f * fabsf(xn));
                    const float th = copysignf(1.f - 2.f / (ex + 1.f), xn);
                    out_mem[(size_t)node * H + c] = (1.f - zg) * th + zg * h;
                }
            }
        }
    }
}

// ---------------- fused fallback (round-7 kernel, used only if ws too small) ----------------
__global__ __launch_bounds__(BLK, 4) void k_gru_fused(
    const int* __restrict__ src, const int* __restrict__ dst, const int* __restrict__ t,
    const float* __restrict__ raw_msg, const float* __restrict__ memory,
    const int* __restrict__ last_update, const float* __restrict__ te_w,
    const float* __restrict__ te_b, const float* __restrict__ b_ih,
    const float* __restrict__ b_hh, const int* __restrict__ win,
    const unsigned short* __restrict__ Bpack,
    float* __restrict__ out_mem, float* __restrict__ out_lu, int E, int N)
{
    __shared__ unsigned short sA[GRPS * NKS * 64 * 8];
    __shared__ int   s_other[MB];
    __shared__ int   s_j[MB];
    __shared__ int   s_has[MB];
    __shared__ float s_dt[MB];

    const int tid   = threadIdx.x;
    const int node0 = blockIdx.x * MB;

    if (tid < MB) {
        int node = node0 + tid;
        int has = 0, j = 0, other = 0; float dt = 0.f;
        if (node < N) {
            int lu = last_update[node];
            int w  = win[node];
            int te = lu;
            if (w >= 0) {
                has = 1;
                int e = (w < E) ? w : (w - E);
                j = e;
                other = (w < E) ? dst[e] : src[e];
                te = t[e];
                dt = (float)(te - lu);
            }
            out_lu[node] = (float)(te > lu ? te : lu);
        }
        s_j[tid] = j; s_other[tid] = other; s_has[tid] = has; s_dt[tid] = dt;
    }
    __syncthreads();

    if (tid < 432) {
        const int nl    = tid % 48;
        const int c0    = tid / 48;
        const int node  = node0 + nl;
        const bool valid = node < N;
        const int has   = s_has[nl];
        const float* memN = memory + (size_t)node * H;
        const float* memO = memory + (size_t)s_other[nl] * H;
        const float* rawJ = raw_msg + (size_t)s_j[nl] * RD;
        const float dt  = s_dt[nl];
        const int grp = nl >> 4;
        const int row = nl & 15;

        float4 va[8], vb[8];
#pragma unroll
        for (int it = 0; it < 8; ++it) {
            const int cc = c0 + it * 9;
            va[it] = make_float4(0.f, 0.f, 0.f, 0.f); vb[it] = va[it];
            if (cc < 67) {
                const int c = cc + 13, kb = c * 8;
                if (c < 26)      { if (has)  { va[it] = ld4g(memO, kb - 104, 100); vb[it] = ld4g(memO, kb - 100, 100); } }
                else if (c < 48) { if (has)  { va[it] = ld4g(rawJ, kb - 208, RD ); vb[it] = ld4g(rawJ, kb - 204, RD ); } }
                else if (c < 64) { }
                else             { if (valid){ va[it] = ld4g(memN, kb - 512, 100); vb[it] = ld4g(memN, kb - 508, 100); } }
            }
        }
#pragma unroll
        for (int it = 0; it < 8; ++it) {
            const int cc = c0 + it * 9;
            if (cc < 67) {
                const int c = cc + 13;
                if (c >= 48 && c < 64 && has) {
                    const int lc = c * 8 - 384;
                    float vv[8];
#pragma unroll
                    for (int q = 0; q < 8; ++q) {
                        int col = lc + q;
                        vv[q] = (col < 100) ? __cosf(fmaf(dt, te_w[col], te_b[col])) : 0.f;
                    }
                    va[it] = make_float4(vv[0], vv[1], vv[2], vv[3]);
                    vb[it] = make_float4(vv[4], vv[5], vv[6], vv[7]);
                }
                int4 sv;
                sv.x = (int)pkbf(va[it].x, va[it].y);
                sv.y = (int)pkbf(va[it].z, va[it].w);
                sv.z = (int)pkbf(vb[it].x, vb[it].y);
                sv.w = (int)pkbf(vb[it].z, vb[it].w);
                {
                    const int ks = c >> 2, sub = c & 3;
                    *(int4*)&sA[((grp * NKS + ks) * 64 + sub * 16 + row) * 8] = sv;
                }
                if (c >= 64 && c < 77) {
                    int4 sm_;
                    sm_.x = has ? sv.x : 0; sm_.y = has ? sv.y : 0;
                    sm_.z = has ? sv.z : 0; sm_.w = has ? sv.w : 0;
                    const int cm = c - 64;
                    const int ks = cm >> 2, sub = cm & 3;
                    *(int4*)&sA[((grp * NKS + ks) * 64 + sub * 16 + row) * 8] = sm_;
                }
            }
        }
    }
    __syncthreads();

    const int wv   = tid >> 6;
    const int lane = tid & 63;
    const int lrow = lane & 15;
    const int lhi  = lane >> 4;

    f32x4 ar[GRPS], az[GRPS], an[GRPS], ah[GRPS];
#pragma unroll
    for (int m = 0; m < GRPS; ++m) { ar[m] = (f32x4)0.f; az[m] = (f32x4)0.f; an[m] = (f32x4)0.f; ah[m] = (f32x4)0.f; }

    __builtin_amdgcn_s_setprio(1);
#pragma unroll
    for (int ks = 0; ks < NKS; ++ks) {
        short8 a0 = *(const short8*)&sA[(0 * NKS + ks) * 512 + lane * 8];
        short8 a1 = *(const short8*)&sA[(1 * NKS + ks) * 512 + lane * 8];
        short8 a2 = *(const short8*)&sA[(2 * NKS + ks) * 512 + lane * 8];
        short8 br = *(const short8*)&Bpack[(((size_t)(     wv) * NKS + ks) * 64 + lane) * 8];
        short8 bz = *(const short8*)&Bpack[(((size_t)( 7 + wv) * NKS + ks) * 64 + lane) * 8];
        short8 bn = (ks < 16)
                  ? *(const short8*)&Bpack[(((size_t)(14 + wv) * NKS + ks) * 64 + lane) * 8]
                  : *(const short8*)&Bpack[(((size_t)(21 + wv) * NKS + ks) * 64 + lane) * 8];
        ar[0] = mfma16(a0, br, ar[0]);  ar[1] = mfma16(a1, br, ar[1]);  ar[2] = mfma16(a2, br, ar[2]);
        az[0] = mfma16(a0, bz, az[0]);  az[1] = mfma16(a1, bz, az[1]);  az[2] = mfma16(a2, bz, az[2]);
        if (ks < 16) { an[0] = mfma16(a0, bn, an[0]);  an[1] = mfma16(a1, bn, an[1]);  an[2] = mfma16(a2, bn, an[2]); }
        else         { ah[0] = mfma16(a0, bn, ah[0]);  ah[1] = mfma16(a1, bn, ah[1]);  ah[2] = mfma16(a2, bn, ah[2]); }
    }
    __builtin_amdgcn_s_setprio(0);

    const int c = wv * 16 + lrow;
    if (c < 100) {
        const float br_ = b_ih[c]       + b_hh[c];
        const float bz_ = b_ih[c + 100] + b_hh[c + 100];
        const float bin = b_ih[c + 200];
        const float bhn = b_hh[c + 200];
        const int ksh = 16 + (c >> 5);
        const int qh  = (c >> 3) & 3;
        const int e   = c & 7;
#pragma unroll
        for (int m = 0; m < GRPS; ++m) {
#pragma unroll
            for (int r = 0; r < 4; ++r) {
                const int node = node0 + m * 16 + lhi * 4 + r;
                if (node < N) {
                    const int rw = lhi * 4 + r;
                    const float h  = bf2f(sA[(m * NKS + ksh) * 512 + (qh * 16 + rw) * 8 + e]);
                    const float rg = 1.f / (1.f + __expf(-(ar[m][r] + br_)));
                    const float zg = 1.f / (1.f + __expf(-(az[m][r] + bz_)));
                    const float xn = an[m][r] + bin + rg * (ah[m][r] + bhn);
                    const float ex = __expf(2.f * fabsf(xn));
                    const float th = copysignf(1.f - 2.f / (ex + 1.f), xn);
                    out_mem[(size_t)node * H + c] = (1.f - zg) * th + zg * h;
                }
            }
        }
    }
}

extern "C" void kernel_launch(void* const* d_in, const int* in_sizes, int n_in,
                              void* d_out, int out_size, void* d_ws, size_t ws_size,
                              hipStream_t stream)
{
    const int*   src         = (const int*)d_in[0];
    const int*   dst         = (const int*)d_in[1];
    const int*   t           = (const int*)d_in[2];
    const float* raw_msg     = (const float*)d_in[3];
    const float* memory      = (const float*)d_in[4];
    const int*   last_update = (const int*)d_in[5];
    const float* te_w        = (const float*)d_in[6];
    const float* te_b        = (const float*)d_in[7];
    const float* w_ih        = (const float*)d_in[8];
    const float* w_hh        = (const float*)d_in[9];
    const float* b_ih        = (const float*)d_in[10];
    const float* b_hh        = (const float*)d_in[11];

    const int E = in_sizes[0];   // 100000
    const int N = in_sizes[5];   // 200000

    float* out    = (float*)d_out;
    float* out_lu = out + (size_t)N * H;

    char* ws = (char*)d_ws;
    int* maxt = (int*)ws;
    int* win  = maxt + N;
    unsigned short* Bpack = (unsigned short*)(win + N);
    int4* meta = (int4*)(Bpack + BPK_N);
    unsigned short* Apack = (unsigned short*)((char*)(meta + N));

    const size_t aux = (size_t)N * 8 + (size_t)BPK_N * 2 + (size_t)N * 16;
    long segN = 0;
    if (ws_size > aux + 4096) segN = (long)((ws_size - aux - 4096) / (CH * 16));
    segN = (segN / MB) * MB;
    if (segN > SEGMAX) segN = SEGMAX;

    k_init<<<(N + 255) / 256, 256, 0, stream>>>(maxt, win, N);
    k_prep<<<(BPK_N + 255) / 256, 256, 0, stream>>>(w_ih, w_hh, Bpack);
    k_maxt<<<(E + 255) / 256, 256, 0, stream>>>(src, dst, t, maxt, E);
    k_win <<<(E + 255) / 256, 256, 0, stream>>>(src, dst, t, maxt, win, E);

    if (segN >= SEGMIN) {
        k_meta<<<(N + 255) / 256, 256, 0, stream>>>(src, dst, t, last_update, win, meta, out_lu, E, N);
        const long Npad = ((long)N + MB - 1) / MB * MB;
        for (long base = 0; base < Npad; base += segN) {
            const long nodes_s = (Npad - base < segN) ? (Npad - base) : segN;
            const int  gth     = (int)(nodes_s * CH);
            k_gather<<<(gth + 255) / 256, 256, 0, stream>>>(raw_msg, memory, te_w, te_b,
                                                            meta, Apack, (int)base, gth, N);
            k_gemm<<<(int)(nodes_s / MB), BLK, 0, stream>>>(Apack, Bpack, b_ih, b_hh,
                                                            out, (int)base, N);
        }
    } else {
        k_gru_fused<<<(N + MB - 1) / MB, BLK, 0, stream>>>(src, dst, t, raw_msg, memory, last_update,
                                                           te_w, te_b, b_ih, b_hh, win, Bpack,
                                                           out, out_lu, E, N);
    }
}

// Round 12
// 210.191 us; speedup vs baseline: 3.3940x; 1.6885x over previous
//
#include <hip/hip_runtime.h>
#include <math.h>

typedef __attribute__((ext_vector_type(8))) short  short8;
typedef __attribute__((ext_vector_type(4))) float  f32x4;

// Problem constants: N=200000, E=100000, H=100, R=172, T=100
static constexpr int H     = 100;
static constexpr int RD    = 172;
static constexpr int WK    = 472;
static constexpr int MSTR  = 104;            // memB row stride (bf16), 208 B
static constexpr int RSTR  = 176;            // rawB row stride (bf16), 352 B
// Padded K layout: [0,104) mem[node] msg | [104,208) mem[other] | [208,384) raw
//                  [384,512) tenc | [512,640) mem[node] hh
static constexpr int NKS   = 20;
static constexpr int MB    = 48;
static constexpr int GRPS  = 3;
static constexpr int BLK   = 448;
static constexpr int NTT   = 28;
static constexpr int BPK_N = NTT * NKS * 64 * 8;   // 286720 bf16

__device__ inline unsigned short f2bf(float x) {
    union { float f; unsigned u; } v; v.f = x;
    return (unsigned short)((v.u + 0x7FFFu + ((v.u >> 16) & 1u)) >> 16);
}
__device__ inline float bf2f(unsigned short b) {
    union { unsigned u; float f; } v; v.u = ((unsigned)b) << 16;
    return v.f;
}
__device__ inline unsigned pkbf(float a, float b) {
    unsigned r;
    asm("v_cvt_pk_bf16_f32 %0, %1, %2" : "=v"(r) : "v"(a), "v"(b));
    return r;
}
__device__ inline f32x4 mfma16(short8 a, short8 b, f32x4 c) {
    return __builtin_amdgcn_mfma_f32_16x16x32_bf16(a, b, c, 0, 0, 0);
}
__device__ inline float4 ld4g(const float* base, int lc, int limit) {
    if (lc + 4 <= limit) return *(const float4*)(base + lc);
    return make_float4(0.f, 0.f, 0.f, 0.f);
}
// global(per-lane scattered 16B) -> LDS(uniform base + lane*16)
__device__ inline void gl16(const unsigned short* g, unsigned short* l) {
    __builtin_amdgcn_global_load_lds(
        (const __attribute__((address_space(1))) void*)g,
        (__attribute__((address_space(3))) void*)l, 16, 0, 0);
}

// ---------------- aggregation ----------------
__global__ __launch_bounds__(256) void k_init(int* __restrict__ maxt, int* __restrict__ win,
                                              int* __restrict__ zb, int N) {
    int i = blockIdx.x * blockDim.x + threadIdx.x;
    if (i < N) { maxt[i] = (int)0x80000000; win[i] = -1; }
    if (i < 128) zb[i] = 0;
}
__global__ __launch_bounds__(256) void k_maxt(const int* __restrict__ src, const int* __restrict__ dst,
                                              const int* __restrict__ t, int* __restrict__ maxt, int E) {
    int j = blockIdx.x * blockDim.x + threadIdx.x;
    if (j < E) {
        int tj = t[j];
        atomicMax(&maxt[src[j]], tj);
        atomicMax(&maxt[dst[j]], tj);
    }
}
__global__ __launch_bounds__(256) void k_win(const int* __restrict__ src, const int* __restrict__ dst,
                                             const int* __restrict__ t, const int* __restrict__ maxt,
                                             int* __restrict__ win, int E) {
    int j = blockIdx.x * blockDim.x + threadIdx.x;
    if (j < E) {
        int tj = t[j];
        int s = src[j], d = dst[j];
        if (maxt[s] == tj) atomicMax(&win[s], j);
        if (maxt[d] == tj) atomicMax(&win[d], j + E);
    }
}
__global__ __launch_bounds__(256) void k_meta(const int* __restrict__ src, const int* __restrict__ dst,
                                              const int* __restrict__ t, const int* __restrict__ last_update,
                                              const int* __restrict__ win, int4* __restrict__ meta,
                                              float* __restrict__ out_lu, int E, int N) {
    int i = blockIdx.x * blockDim.x + threadIdx.x;
    if (i >= N) return;
    int lu = last_update[i], w = win[i];
    int j = 0, other = 0, has = 0, te = lu; float dt = 0.f;
    if (w >= 0) {
        has = 1;
        int e = (w < E) ? w : (w - E);
        j = e;
        other = (w < E) ? dst[e] : src[e];
        te = t[e];
        dt = (float)(te - lu);
    }
    out_lu[i] = (float)(te > lu ? te : lu);
    int4 m; m.x = j; m.y = other; m.z = has; m.w = __float_as_int(dt);
    meta[i] = m;
}

// ---------------- bf16 pre-conversion (streaming, coalesced) ----------------
__global__ __launch_bounds__(256) void k_cvt(const float* __restrict__ mem, const float* __restrict__ raw,
                                             unsigned short* __restrict__ memB, unsigned short* __restrict__ rawB,
                                             int N, int E) {
    int i = blockIdx.x * 256 + threadIdx.x;
    const int nm = N * 13;                 // 13 x 8-elem chunks per mem row
    if (i < nm) {
        int row = i / 13, o = (i - row * 13) * 8;
        float4 a = ld4g(mem + (size_t)row * 100, o, 100);
        float4 b = ld4g(mem + (size_t)row * 100, o + 4, 100);
        int4 s; s.x = (int)pkbf(a.x, a.y); s.y = (int)pkbf(a.z, a.w);
        s.z = (int)pkbf(b.x, b.y); s.w = (int)pkbf(b.z, b.w);
        *(int4*)&memB[(size_t)row * MSTR + o] = s;
    } else if (i < nm + E * 22) {          // 22 chunks per raw row
        int k = i - nm;
        int row = k / 22, o = (k - row * 22) * 8;
        float4 a = ld4g(raw + (size_t)row * 172, o, 172);
        float4 b = ld4g(raw + (size_t)row * 172, o + 4, 172);
        int4 s; s.x = (int)pkbf(a.x, a.y); s.y = (int)pkbf(a.z, a.w);
        s.z = (int)pkbf(b.x, b.y); s.w = (int)pkbf(b.z, b.w);
        *(int4*)&rawB[(size_t)row * RSTR + o] = s;
    }
}

// ---------------- weight prep ----------------
__global__ __launch_bounds__(256) void k_prep(const float* __restrict__ w_ih, const float* __restrict__ w_hh,
                                              unsigned short* __restrict__ B) {
    int idx = blockIdx.x * 256 + threadIdx.x;
    if (idx >= BPK_N) return;
    int jj   = idx & 7;
    int lane = (idx >> 3) & 63;
    int rest = idx >> 9;
    int ks   = rest % NKS;
    int tile = rest / NKS;
    int kk   = ks * 32 + ((lane >> 4) << 3) + jj;
    float v = 0.f;
    if (tile < 21) {
        int gate = tile / 7;
        int tcol = (tile % 7) * 16 + (lane & 15);
        if (tcol < 100) {
            if (kk < 512) {
                int col = -1;
                if (kk < 100)                   col = kk;
                else if (kk >= 104 && kk < 204) col = kk - 4;
                else if (kk >= 208 && kk < 380) col = kk - 8;
                else if (kk >= 384 && kk < 484) col = kk - 12;
                if (col >= 0) v = w_ih[(gate * 100 + tcol) * WK + col];
            } else {
                int khh = kk - 512;
                if (gate < 2 && khh < 100)
                    v = w_hh[(gate * 100 + tcol) * H + khh];
            }
        }
    } else {
        int tcol = (tile - 21) * 16 + (lane & 15);
        int khh  = kk - 512;
        if (tcol < 100 && khh >= 0 && khh < 100)
            v = w_hh[(200 + tcol) * H + khh];
    }
    B[idx] = f2bf(v);
}

// ---------------- fused GRU: global_load_lds A-staging + MFMA ----------------
__global__ __launch_bounds__(BLK, 4) void k_gru2(
    const unsigned short* __restrict__ memB, const unsigned short* __restrict__ rawB,
    const float* __restrict__ te_w, const float* __restrict__ te_b,
    const float* __restrict__ b_ih, const float* __restrict__ b_hh,
    const int4* __restrict__ meta, const unsigned short* __restrict__ zb,
    const unsigned short* __restrict__ Bpack,
    float* __restrict__ out_mem, int N)
{
    __shared__ unsigned short sA[GRPS * NKS * 512];   // 60 tiles x 1KB = 61440 B, linear frags

    const int tid  = threadIdx.x;
    const int wv   = tid >> 6;
    const int lane = tid & 63;
    const int q    = lane >> 4;
    const int row  = lane & 15;
    const int node0 = blockIdx.x * MB;

    // --- staging: 48 tiles via global_load_lds, 12 tenc tiles via VALU ---
#pragma unroll
    for (int g = 0; g < GRPS; ++g) {
        const int node_g = node0 + g * 16 + row;
        const bool val = node_g < N;
        const int4 m = val ? meta[node_g] : make_int4(0, 0, 0, 0);
        const bool has = m.z != 0;
        const float dt = __int_as_float(m.w);
        const unsigned short* pmm = has ? memB + (size_t)node_g * MSTR : zb;
        const unsigned short* pot = has ? memB + (size_t)m.y * MSTR   : zb;
        const unsigned short* prw = has ? rawB + (size_t)m.x * RSTR   : zb;
        const unsigned short* phh = val ? memB + (size_t)node_g * MSTR : zb;

        int ks0 = (wv - g * 20) % 7; if (ks0 < 0) ks0 += 7;
        for (int ks = ks0; ks < NKS; ks += 7) {
            if (ks >= 12 && ks < 16) {
                // tenc tile: compute 8 values, pack, ds_write
                const int o = (ks - 12) * 32 + q * 8;
                float4 w0 = ld4g(te_w, o, 100), w1 = ld4g(te_w, o + 4, 100);
                float4 c0 = ld4g(te_b, o, 100), c1 = ld4g(te_b, o + 4, 100);
                const float hf = has ? 1.f : 0.f;
                float v0 = hf * __cosf(fmaf(dt, w0.x, c0.x));
                float v1 = hf * __cosf(fmaf(dt, w0.y, c0.y));
                float v2 = hf * __cosf(fmaf(dt, w0.z, c0.z));
                float v3 = hf * __cosf(fmaf(dt, w0.w, c0.w));
                float v4 = hf * __cosf(fmaf(dt, w1.x, c1.x));
                float v5 = hf * __cosf(fmaf(dt, w1.y, c1.y));
                float v6 = hf * __cosf(fmaf(dt, w1.z, c1.z));
                float v7 = hf * __cosf(fmaf(dt, w1.w, c1.w));
                int4 sv;
                sv.x = (int)pkbf(v0, v1); sv.y = (int)pkbf(v2, v3);
                sv.z = (int)pkbf(v4, v5); sv.w = (int)pkbf(v6, v7);
                *(int4*)&sA[(g * NKS + ks) * 512 + lane * 8] = sv;
            } else {
                const int k0 = ks * 32 + q * 8;
                const unsigned short* s =
                    (k0 < 104) ? pmm + k0 :
                    (k0 < 208) ? pot + (k0 - 104) :
                    (k0 < 384) ? prw + (k0 - 208) :
                                 phh + (k0 - 512);
                gl16(s, &sA[(g * NKS + ks) * 512]);   // HW: dest + lane*16
            }
        }
    }
    __syncthreads();   // drains vmcnt (global_load_lds) + lgkmcnt

    // --- MFMA: wave wv owns cols wv*16..+15 of all gates ---
    f32x4 ar[GRPS], az[GRPS], an[GRPS], ah[GRPS];
#pragma unroll
    for (int m = 0; m < GRPS; ++m) { ar[m] = (f32x4)0.f; az[m] = (f32x4)0.f; an[m] = (f32x4)0.f; ah[m] = (f32x4)0.f; }

    __builtin_amdgcn_s_setprio(1);
#pragma unroll
    for (int ks = 0; ks < NKS; ++ks) {
        short8 a0 = *(const short8*)&sA[(0 * NKS + ks) * 512 + lane * 8];
        short8 a1 = *(const short8*)&sA[(1 * NKS + ks) * 512 + lane * 8];
        short8 a2 = *(const short8*)&sA[(2 * NKS + ks) * 512 + lane * 8];
        short8 br = *(const short8*)&Bpack[(((size_t)(     wv) * NKS + ks) * 64 + lane) * 8];
        short8 bz = *(const short8*)&Bpack[(((size_t)( 7 + wv) * NKS + ks) * 64 + lane) * 8];
        short8 bn = (ks < 16)
                  ? *(const short8*)&Bpack[(((size_t)(14 + wv) * NKS + ks) * 64 + lane) * 8]
                  : *(const short8*)&Bpack[(((size_t)(21 + wv) * NKS + ks) * 64 + lane) * 8];
        ar[0] = mfma16(a0, br, ar[0]);  ar[1] = mfma16(a1, br, ar[1]);  ar[2] = mfma16(a2, br, ar[2]);
        az[0] = mfma16(a0, bz, az[0]);  az[1] = mfma16(a1, bz, az[1]);  az[2] = mfma16(a2, bz, az[2]);
        if (ks < 16) { an[0] = mfma16(a0, bn, an[0]);  an[1] = mfma16(a1, bn, an[1]);  an[2] = mfma16(a2, bn, an[2]); }
        else         { ah[0] = mfma16(a0, bn, ah[0]);  ah[1] = mfma16(a1, bn, ah[1]);  ah[2] = mfma16(a2, bn, ah[2]); }
    }
    __builtin_amdgcn_s_setprio(0);

    // --- in-register gates + store; h from staged hh section (bf16) ---
    const int c = wv * 16 + (lane & 15);
    const int lhi = lane >> 4;
    if (c < 100) {
        const float br_ = b_ih[c]       + b_hh[c];
        const float bz_ = b_ih[c + 100] + b_hh[c + 100];
        const float bin = b_ih[c + 200];
        const float bhn = b_hh[c + 200];
        const int ksh = 16 + (c >> 5);
        const int qh  = (c >> 3) & 3;
        const int e   = c & 7;
#pragma unroll
        for (int m = 0; m < GRPS; ++m) {
#pragma unroll
            for (int r = 0; r < 4; ++r) {
                const int node = node0 + m * 16 + lhi * 4 + r;
                if (node < N) {
                    const int rw = lhi * 4 + r;
                    const float h  = bf2f(sA[(m * NKS + ksh) * 512 + (qh * 16 + rw) * 8 + e]);
                    const float rg = 1.f / (1.f + __expf(-(ar[m][r] + br_)));
                    const float zg = 1.f / (1.f + __expf(-(az[m][r] + bz_)));
                    const float xn = an[m][r] + bin + rg * (ah[m][r] + bhn);
                    const float ex = __expf(2.f * fabsf(xn));
                    const float th = copysignf(1.f - 2.f / (ex + 1.f), xn);
                    out_mem[(size_t)node * H + c] = (1.f - zg) * th + zg * h;
                }
            }
        }
    }
}

// ---------------- fused fallback (r7-style) if ws too small ----------------
__global__ __launch_bounds__(BLK, 4) void k_gru_fused(
    const int* __restrict__ src, const int* __restrict__ dst, const int* __restrict__ t,
    const float* __restrict__ raw_msg, const float* __restrict__ memory,
    const int* __restrict__ last_update, const float* __restrict__ te_w,
    const float* __restrict__ te_b, const float* __restrict__ b_ih,
    const float* __restrict__ b_hh, const int* __restrict__ win,
    const unsigned short* __restrict__ Bpack,
    float* __restrict__ out_mem, float* __restrict__ out_lu, int E, int N)
{
    __shared__ unsigned short sA[GRPS * NKS * 512];
    __shared__ int   s_other[MB];
    __shared__ int   s_j[MB];
    __shared__ int   s_has[MB];
    __shared__ float s_dt[MB];

    const int tid   = threadIdx.x;
    const int node0 = blockIdx.x * MB;

    if (tid < MB) {
        int node = node0 + tid;
        int has = 0, j = 0, other = 0; float dt = 0.f;
        if (node < N) {
            int lu = last_update[node];
            int w  = win[node];
            int te = lu;
            if (w >= 0) {
                has = 1;
                int e = (w < E) ? w : (w - E);
                j = e;
                other = (w < E) ? dst[e] : src[e];
                te = t[e];
                dt = (float)(te - lu);
            }
            out_lu[node] = (float)(te > lu ? te : lu);
        }
        s_j[tid] = j; s_other[tid] = other; s_has[tid] = has; s_dt[tid] = dt;
    }
    __syncthreads();

    if (tid < 432) {
        const int nl    = tid % 48;
        const int c0    = tid / 48;
        const int node  = node0 + nl;
        const bool valid = node < N;
        const int has   = s_has[nl];
        const float* memN = memory + (size_t)node * H;
        const float* memO = memory + (size_t)s_other[nl] * H;
        const float* rawJ = raw_msg + (size_t)s_j[nl] * RD;
        const float dt  = s_dt[nl];
        const int grp = nl >> 4;
        const int row = nl & 15;

        float4 va[8], vb[8];
#pragma unroll
        for (int it = 0; it < 8; ++it) {
            const int cc = c0 + it * 9;
            va[it] = make_float4(0.f, 0.f, 0.f, 0.f); vb[it] = va[it];
            if (cc < 67) {
                const int c = cc + 13, kb = c * 8;
                if (c < 26)      { if (has)  { va[it] = ld4g(memO, kb - 104, 100); vb[it] = ld4g(memO, kb - 100, 100); } }
                else if (c < 48) { if (has)  { va[it] = ld4g(rawJ, kb - 208, RD ); vb[it] = ld4g(rawJ, kb - 204, RD ); } }
                else if (c < 64) { }
                else             { if (valid){ va[it] = ld4g(memN, kb - 512, 100); vb[it] = ld4g(memN, kb - 508, 100); } }
            }
        }
#pragma unroll
        for (int it = 0; it < 8; ++it) {
            const int cc = c0 + it * 9;
            if (cc < 67) {
                const int c = cc + 13;
                if (c >= 48 && c < 64 && has) {
                    const int lc = c * 8 - 384;
                    float vv[8];
#pragma unroll
                    for (int x = 0; x < 8; ++x) {
                        int col = lc + x;
                        vv[x] = (col < 100) ? __cosf(fmaf(dt, te_w[col], te_b[col])) : 0.f;
                    }
                    va[it] = make_float4(vv[0], vv[1], vv[2], vv[3]);
                    vb[it] = make_float4(vv[4], vv[5], vv[6], vv[7]);
                }
                int4 sv;
                sv.x = (int)pkbf(va[it].x, va[it].y);
                sv.y = (int)pkbf(va[it].z, va[it].w);
                sv.z = (int)pkbf(vb[it].x, vb[it].y);
                sv.w = (int)pkbf(vb[it].z, vb[it].w);
                {
                    const int ks = c >> 2, sub = c & 3;
                    *(int4*)&sA[((grp * NKS + ks) * 64 + sub * 16 + row) * 8] = sv;
                }
                if (c >= 64 && c < 77) {
                    int4 sm_;
                    sm_.x = has ? sv.x : 0; sm_.y = has ? sv.y : 0;
                    sm_.z = has ? sv.z : 0; sm_.w = has ? sv.w : 0;
                    const int cm = c - 64;
                    const int ks = cm >> 2, sub = cm & 3;
                    *(int4*)&sA[((grp * NKS + ks) * 64 + sub * 16 + row) * 8] = sm_;
                }
            }
        }
    }
    __syncthreads();

    const int wv   = tid >> 6;
    const int lane = tid & 63;
    const int lrow = lane & 15;
    const int lhi  = lane >> 4;

    f32x4 ar[GRPS], az[GRPS], an[GRPS], ah[GRPS];
#pragma unroll
    for (int m = 0; m < GRPS; ++m) { ar[m] = (f32x4)0.f; az[m] = (f32x4)0.f; an[m] = (f32x4)0.f; ah[m] = (f32x4)0.f; }

    __builtin_amdgcn_s_setprio(1);
#pragma unroll
    for (int ks = 0; ks < NKS; ++ks) {
        short8 a0 = *(const short8*)&sA[(0 * NKS + ks) * 512 + lane * 8];
        short8 a1 = *(const short8*)&sA[(1 * NKS + ks) * 512 + lane * 8];
        short8 a2 = *(const short8*)&sA[(2 * NKS + ks) * 512 + lane * 8];
        short8 br = *(const short8*)&Bpack[(((size_t)(     wv) * NKS + ks) * 64 + lane) * 8];
        short8 bz = *(const short8*)&Bpack[(((size_t)( 7 + wv) * NKS + ks) * 64 + lane) * 8];
        short8 bn = (ks < 16)
                  ? *(const short8*)&Bpack[(((size_t)(14 + wv) * NKS + ks) * 64 + lane) * 8]
                  : *(const short8*)&Bpack[(((size_t)(21 + wv) * NKS + ks) * 64 + lane) * 8];
        ar[0] = mfma16(a0, br, ar[0]);  ar[1] = mfma16(a1, br, ar[1]);  ar[2] = mfma16(a2, br, ar[2]);
        az[0] = mfma16(a0, bz, az[0]);  az[1] = mfma16(a1, bz, az[1]);  az[2] = mfma16(a2, bz, az[2]);
        if (ks < 16) { an[0] = mfma16(a0, bn, an[0]);  an[1] = mfma16(a1, bn, an[1]);  an[2] = mfma16(a2, bn, an[2]); }
        else         { ah[0] = mfma16(a0, bn, ah[0]);  ah[1] = mfma16(a1, bn, ah[1]);  ah[2] = mfma16(a2, bn, ah[2]); }
    }
    __builtin_amdgcn_s_setprio(0);

    const int c = wv * 16 + lrow;
    if (c < 100) {
        const float br_ = b_ih[c]       + b_hh[c];
        const float bz_ = b_ih[c + 100] + b_hh[c + 100];
        const float bin = b_ih[c + 200];
        const float bhn = b_hh[c + 200];
        const int ksh = 16 + (c >> 5);
        const int qh  = (c >> 3) & 3;
        const int e   = c & 7;
#pragma unroll
        for (int m = 0; m < GRPS; ++m) {
#pragma unroll
            for (int r = 0; r < 4; ++r) {
                const int node = node0 + m * 16 + lhi * 4 + r;
                if (node < N) {
                    const int rw = lhi * 4 + r;
                    const float h  = bf2f(sA[(m * NKS + ksh) * 512 + (qh * 16 + rw) * 8 + e]);
                    const float rg = 1.f / (1.f + __expf(-(ar[m][r] + br_)));
                    const float zg = 1.f / (1.f + __expf(-(az[m][r] + bz_)));
                    const float xn = an[m][r] + bin + rg * (ah[m][r] + bhn);
                    const float ex = __expf(2.f * fabsf(xn));
                    const float th = copysignf(1.f - 2.f / (ex + 1.f), xn);
                    out_mem[(size_t)node * H + c] = (1.f - zg) * th + zg * h;
                }
            }
        }
    }
}

extern "C" void kernel_launch(void* const* d_in, const int* in_sizes, int n_in,
                              void* d_out, int out_size, void* d_ws, size_t ws_size,
                              hipStream_t stream)
{
    const int*   src         = (const int*)d_in[0];
    const int*   dst         = (const int*)d_in[1];
    const int*   t           = (const int*)d_in[2];
    const float* raw_msg     = (const float*)d_in[3];
    const float* memory      = (const float*)d_in[4];
    const int*   last_update = (const int*)d_in[5];
    const float* te_w        = (const float*)d_in[6];
    const float* te_b        = (const float*)d_in[7];
    const float* w_ih        = (const float*)d_in[8];
    const float* w_hh        = (const float*)d_in[9];
    const float* b_ih        = (const float*)d_in[10];
    const float* b_hh        = (const float*)d_in[11];

    const int E = in_sizes[0];   // 100000
    const int N = in_sizes[5];   // 200000

    float* out    = (float*)d_out;
    float* out_lu = out + (size_t)N * H;

    // ws layout (16B-aligned pieces)
    char* ws = (char*)d_ws;
    int* maxt = (int*)ws;                                  // N ints
    int* win  = maxt + N;                                  // N ints
    unsigned short* Bpack = (unsigned short*)(win + N);    // BPK_N
    int4* meta = (int4*)(Bpack + BPK_N);                   // N int4
    unsigned short* zb   = (unsigned short*)(meta + N);    // 256 ushorts
    unsigned short* memB = zb + 256;                       // N*104 + 32
    unsigned short* rawB = memB + (size_t)N * MSTR + 32;   // E*176
    const size_t need = (size_t)((char*)(rawB + (size_t)E * RSTR) - ws) + 64;

    k_init<<<(N + 255) / 256, 256, 0, stream>>>(maxt, win, (int*)zb, N);
    k_prep<<<(BPK_N + 255) / 256, 256, 0, stream>>>(w_ih, w_hh, Bpack);
    k_maxt<<<(E + 255) / 256, 256, 0, stream>>>(src, dst, t, maxt, E);
    k_win <<<(E + 255) / 256, 256, 0, stream>>>(src, dst, t, maxt, win, E);

    if (ws_size >= need) {
        const int ncvt = N * 13 + E * 22;
        k_cvt<<<(ncvt + 255) / 256, 256, 0, stream>>>(memory, raw_msg, memB, rawB, N, E);
        k_meta<<<(N + 255) / 256, 256, 0, stream>>>(src, dst, t, last_update, win, meta, out_lu, E, N);
        k_gru2<<<(N + MB - 1) / MB, BLK, 0, stream>>>(memB, rawB, te_w, te_b, b_ih, b_hh,
                                                      meta, zb, Bpack, out, N);
    } else {
        k_gru_fused<<<(N + MB - 1) / MB, BLK, 0, stream>>>(src, dst, t, raw_msg, memory, last_update,
                                                           te_w, te_b, b_ih, b_hh, win, Bpack,
                                                           out, out_lu, E, N);
    }
}

// Round 13
// 205.783 us; speedup vs baseline: 3.4667x; 1.0214x over previous
//
#include <hip/hip_runtime.h>
#include <math.h>

typedef __attribute__((ext_vector_type(8))) short  short8;
typedef __attribute__((ext_vector_type(4))) float  f32x4;

// Problem constants: N=200000, E=100000, H=100, R=172, T=100
static constexpr int H     = 100;
static constexpr int RD    = 172;
static constexpr int WK    = 472;
static constexpr int MSTR  = 104;            // memB row stride (bf16)
static constexpr int RSTR  = 176;            // rawB row stride (bf16)
// Padded K layout: [0,104) mem[node] msg | [104,208) mem[other] | [208,384) raw
//                  [384,512) tenc | [512,640) mem[node] hh
static constexpr int NKS   = 20;
static constexpr int MB    = 32;             // nodes per block (2 x 16-row groups)
static constexpr int GRPS  = 2;
static constexpr int BLK   = 448;            // 7 waves; wave wv owns cols wv*16..+15
static constexpr int NTT   = 28;
static constexpr int BPK_N = NTT * NKS * 64 * 8;   // 286720 bf16

// fallback (r7-style) constants
static constexpr int FB_MB = 48;
static constexpr int FB_GR = 3;

__device__ inline unsigned short f2bf(float x) {
    union { float f; unsigned u; } v; v.f = x;
    return (unsigned short)((v.u + 0x7FFFu + ((v.u >> 16) & 1u)) >> 16);
}
__device__ inline float bf2f(unsigned short b) {
    union { unsigned u; float f; } v; v.u = ((unsigned)b) << 16;
    return v.f;
}
__device__ inline unsigned pkbf(float a, float b) {
    unsigned r;
    asm("v_cvt_pk_bf16_f32 %0, %1, %2" : "=v"(r) : "v"(a), "v"(b));
    return r;
}
__device__ inline float frcp(float x) {
    float r;
    asm("v_rcp_f32 %0, %1" : "=v"(r) : "v"(x));
    return r;
}
__device__ inline f32x4 mfma16(short8 a, short8 b, f32x4 c) {
    return __builtin_amdgcn_mfma_f32_16x16x32_bf16(a, b, c, 0, 0, 0);
}
__device__ inline float4 ld4g(const float* base, int lc, int limit) {
    if (lc + 4 <= limit) return *(const float4*)(base + lc);
    return make_float4(0.f, 0.f, 0.f, 0.f);
}
__device__ inline void gl16(const unsigned short* g, unsigned short* l) {
    __builtin_amdgcn_global_load_lds(
        (const __attribute__((address_space(1))) void*)g,
        (__attribute__((address_space(3))) void*)l, 16, 0, 0);
}

// ---------------- aggregation ----------------
__global__ __launch_bounds__(256) void k_init(int* __restrict__ maxt, int* __restrict__ win,
                                              int* __restrict__ zb, int N) {
    int i = blockIdx.x * blockDim.x + threadIdx.x;
    if (i < N) { maxt[i] = (int)0x80000000; win[i] = -1; }
    if (i < 128) zb[i] = 0;
}
__global__ __launch_bounds__(256) void k_maxt(const int* __restrict__ src, const int* __restrict__ dst,
                                              const int* __restrict__ t, int* __restrict__ maxt, int E) {
    int j = blockIdx.x * blockDim.x + threadIdx.x;
    if (j < E) {
        int tj = t[j];
        atomicMax(&maxt[src[j]], tj);
        atomicMax(&maxt[dst[j]], tj);
    }
}
__global__ __launch_bounds__(256) void k_win(const int* __restrict__ src, const int* __restrict__ dst,
                                             const int* __restrict__ t, const int* __restrict__ maxt,
                                             int* __restrict__ win, int E) {
    int j = blockIdx.x * blockDim.x + threadIdx.x;
    if (j < E) {
        int tj = t[j];
        int s = src[j], d = dst[j];
        if (maxt[s] == tj) atomicMax(&win[s], j);
        if (maxt[d] == tj) atomicMax(&win[d], j + E);
    }
}
__global__ __launch_bounds__(256) void k_meta(const int* __restrict__ src, const int* __restrict__ dst,
                                              const int* __restrict__ t, const int* __restrict__ last_update,
                                              const int* __restrict__ win, int4* __restrict__ meta,
                                              float* __restrict__ out_lu, int E, int N) {
    int i = blockIdx.x * blockDim.x + threadIdx.x;
    if (i >= N) return;
    int lu = last_update[i], w = win[i];
    int j = 0, other = 0, has = 0, te = lu; float dt = 0.f;
    if (w >= 0) {
        has = 1;
        int e = (w < E) ? w : (w - E);
        j = e;
        other = (w < E) ? dst[e] : src[e];
        te = t[e];
        dt = (float)(te - lu);
    }
    out_lu[i] = (float)(te > lu ? te : lu);
    int4 m; m.x = j; m.y = other; m.z = has; m.w = __float_as_int(dt);
    meta[i] = m;
}

// ---------------- bf16 pre-conversion ----------------
__global__ __launch_bounds__(256) void k_cvt(const float* __restrict__ mem, const float* __restrict__ raw,
                                             unsigned short* __restrict__ memB, unsigned short* __restrict__ rawB,
                                             int N, int E) {
    int i = blockIdx.x * 256 + threadIdx.x;
    const int nm = N * 13;
    if (i < nm) {
        int row = i / 13, o = (i - row * 13) * 8;
        float4 a = ld4g(mem + (size_t)row * 100, o, 100);
        float4 b = ld4g(mem + (size_t)row * 100, o + 4, 100);
        int4 s; s.x = (int)pkbf(a.x, a.y); s.y = (int)pkbf(a.z, a.w);
        s.z = (int)pkbf(b.x, b.y); s.w = (int)pkbf(b.z, b.w);
        *(int4*)&memB[(size_t)row * MSTR + o] = s;
    } else if (i < nm + E * 22) {
        int k = i - nm;
        int row = k / 22, o = (k - row * 22) * 8;
        float4 a = ld4g(raw + (size_t)row * 172, o, 172);
        float4 b = ld4g(raw + (size_t)row * 172, o + 4, 172);
        int4 s; s.x = (int)pkbf(a.x, a.y); s.y = (int)pkbf(a.z, a.w);
        s.z = (int)pkbf(b.x, b.y); s.w = (int)pkbf(b.z, b.w);
        *(int4*)&rawB[(size_t)row * RSTR + o] = s;
    }
}

// ---------------- weight prep ----------------
__global__ __launch_bounds__(256) void k_prep(const float* __restrict__ w_ih, const float* __restrict__ w_hh,
                                              unsigned short* __restrict__ B) {
    int idx = blockIdx.x * 256 + threadIdx.x;
    if (idx >= BPK_N) return;
    int jj   = idx & 7;
    int lane = (idx >> 3) & 63;
    int rest = idx >> 9;
    int ks   = rest % NKS;
    int tile = rest / NKS;
    int kk   = ks * 32 + ((lane >> 4) << 3) + jj;
    float v = 0.f;
    if (tile < 21) {
        int gate = tile / 7;
        int tcol = (tile % 7) * 16 + (lane & 15);
        if (tcol < 100) {
            if (kk < 512) {
                int col = -1;
                if (kk < 100)                   col = kk;
                else if (kk >= 104 && kk < 204) col = kk - 4;
                else if (kk >= 208 && kk < 380) col = kk - 8;
                else if (kk >= 384 && kk < 484) col = kk - 12;
                if (col >= 0) v = w_ih[(gate * 100 + tcol) * WK + col];
            } else {
                int khh = kk - 512;
                if (gate < 2 && khh < 100)
                    v = w_hh[(gate * 100 + tcol) * H + khh];
            }
        }
    } else {
        int tcol = (tile - 21) * 16 + (lane & 15);
        int khh  = kk - 512;
        if (tcol < 100 && khh >= 0 && khh < 100)
            v = w_hh[(200 + tcol) * H + khh];
    }
    B[idx] = f2bf(v);
}

// ---------------- fused GRU: gl16 staging, 4 blocks/CU ----------------
__global__ __launch_bounds__(BLK, 7) void k_gru2(
    const unsigned short* __restrict__ memB, const unsigned short* __restrict__ rawB,
    const float* __restrict__ te_w, const float* __restrict__ te_b,
    const float* __restrict__ b_ih, const float* __restrict__ b_hh,
    const int4* __restrict__ meta, const unsigned short* __restrict__ zb,
    const unsigned short* __restrict__ Bpack,
    float* __restrict__ out_mem, int N)
{
    __shared__ unsigned short sA[GRPS * NKS * 512];   // 40960 B -> 4 blocks/CU

    const int tid  = threadIdx.x;
    const int wv   = tid >> 6;
    const int lane = tid & 63;
    const int q    = lane >> 4;
    const int row  = lane & 15;
    const int node0 = blockIdx.x * MB;

#pragma unroll
    for (int g = 0; g < GRPS; ++g) {
        const int node_g = node0 + g * 16 + row;
        const bool val = node_g < N;
        const int4 m = val ? meta[node_g] : make_int4(0, 0, 0, 0);
        const bool has = m.z != 0;
        const float dt = __int_as_float(m.w);
        const unsigned short* pmm = has ? memB + (size_t)node_g * MSTR : zb;
        const unsigned short* pot = has ? memB + (size_t)m.y * MSTR   : zb;
        const unsigned short* prw = has ? rawB + (size_t)m.x * RSTR   : zb;
        const unsigned short* phh = val ? memB + (size_t)node_g * MSTR : zb;

        // pass 1: issue gl16 for non-tenc tiles of this g (loads fly under pass 2)
#pragma unroll
        for (int ii = 0; ii < 3; ++ii) {
            const int ks = wv + 7 * ii;
            if (ks < NKS && (ks < 12 || ks >= 16)) {
                const int k0 = ks * 32 + q * 8;
                const unsigned short* s =
                    (k0 < 104) ? pmm + k0 :
                    (k0 < 208) ? pot + (k0 - 104) :
                    (k0 < 384) ? prw + (k0 - 208) :
                                 phh + (k0 - 512);
                gl16(s, &sA[(g * NKS + ks) * 512]);
            }
        }
        // pass 2: tenc tiles (pure VALU + ds_write)
#pragma unroll
        for (int ii = 0; ii < 3; ++ii) {
            const int ks = wv + 7 * ii;
            if (ks >= 12 && ks < 16) {
                const int o = (ks - 12) * 32 + q * 8;
                float4 w0 = ld4g(te_w, o, 100), w1 = ld4g(te_w, o + 4, 100);
                float4 c0 = ld4g(te_b, o, 100), c1 = ld4g(te_b, o + 4, 100);
                const float hf = has ? 1.f : 0.f;
                float v0 = hf * __cosf(fmaf(dt, w0.x, c0.x));
                float v1 = hf * __cosf(fmaf(dt, w0.y, c0.y));
                float v2 = hf * __cosf(fmaf(dt, w0.z, c0.z));
                float v3 = hf * __cosf(fmaf(dt, w0.w, c0.w));
                float v4 = hf * __cosf(fmaf(dt, w1.x, c1.x));
                float v5 = hf * __cosf(fmaf(dt, w1.y, c1.y));
                float v6 = hf * __cosf(fmaf(dt, w1.z, c1.z));
                float v7 = hf * __cosf(fmaf(dt, w1.w, c1.w));
                int4 sv;
                sv.x = (int)pkbf(v0, v1); sv.y = (int)pkbf(v2, v3);
                sv.z = (int)pkbf(v4, v5); sv.w = (int)pkbf(v6, v7);
                *(int4*)&sA[(g * NKS + ks) * 512 + lane * 8] = sv;
            }
        }
    }
    __syncthreads();   // drains vmcnt (global_load_lds) + lgkmcnt

    // --- MFMA ---
    f32x4 ar[GRPS], az[GRPS], an[GRPS], ah[GRPS];
#pragma unroll
    for (int m = 0; m < GRPS; ++m) { ar[m] = (f32x4)0.f; az[m] = (f32x4)0.f; an[m] = (f32x4)0.f; ah[m] = (f32x4)0.f; }

    __builtin_amdgcn_s_setprio(1);
#pragma unroll
    for (int ks = 0; ks < NKS; ++ks) {
        short8 a0 = *(const short8*)&sA[(0 * NKS + ks) * 512 + lane * 8];
        short8 a1 = *(const short8*)&sA[(1 * NKS + ks) * 512 + lane * 8];
        short8 br = *(const short8*)&Bpack[(((size_t)(     wv) * NKS + ks) * 64 + lane) * 8];
        short8 bz = *(const short8*)&Bpack[(((size_t)( 7 + wv) * NKS + ks) * 64 + lane) * 8];
        short8 bn = (ks < 16)
                  ? *(const short8*)&Bpack[(((size_t)(14 + wv) * NKS + ks) * 64 + lane) * 8]
                  : *(const short8*)&Bpack[(((size_t)(21 + wv) * NKS + ks) * 64 + lane) * 8];
        ar[0] = mfma16(a0, br, ar[0]);  ar[1] = mfma16(a1, br, ar[1]);
        az[0] = mfma16(a0, bz, az[0]);  az[1] = mfma16(a1, bz, az[1]);
        if (ks < 16) { an[0] = mfma16(a0, bn, an[0]);  an[1] = mfma16(a1, bn, an[1]); }
        else         { ah[0] = mfma16(a0, bn, ah[0]);  ah[1] = mfma16(a1, bn, ah[1]); }
    }
    __builtin_amdgcn_s_setprio(0);

    // --- gates + store (fast rcp); h from staged hh section ---
    const int c = wv * 16 + row;
    if (c < 100) {
        const float br_ = b_ih[c]       + b_hh[c];
        const float bz_ = b_ih[c + 100] + b_hh[c + 100];
        const float bin = b_ih[c + 200];
        const float bhn = b_hh[c + 200];
        const int ksh = 16 + (c >> 5);
        const int qh  = (c >> 3) & 3;
        const int e   = c & 7;
#pragma unroll
        for (int m = 0; m < GRPS; ++m) {
#pragma unroll
            for (int r = 0; r < 4; ++r) {
                const int node = node0 + m * 16 + q * 4 + r;
                if (node < N) {
                    const int rw = q * 4 + r;
                    const float h  = bf2f(sA[(m * NKS + ksh) * 512 + (qh * 16 + rw) * 8 + e]);
                    const float rg = frcp(1.f + __expf(-(ar[m][r] + br_)));
                    const float zg = frcp(1.f + __expf(-(az[m][r] + bz_)));
                    const float xn = an[m][r] + bin + rg * (ah[m][r] + bhn);
                    const float th = copysignf(1.f - 2.f * frcp(__expf(2.f * fabsf(xn)) + 1.f), xn);
                    out_mem[(size_t)node * H + c] = (1.f - zg) * th + zg * h;
                }
            }
        }
    }
}

// ---------------- fused fallback (r7-style, own 48/3 constants) ----------------
__global__ __launch_bounds__(BLK, 4) void k_gru_fused(
    const int* __restrict__ src, const int* __restrict__ dst, const int* __restrict__ t,
    const float* __restrict__ raw_msg, const float* __restrict__ memory,
    const int* __restrict__ last_update, const float* __restrict__ te_w,
    const float* __restrict__ te_b, const float* __restrict__ b_ih,
    const float* __restrict__ b_hh, const int* __restrict__ win,
    const unsigned short* __restrict__ Bpack,
    float* __restrict__ out_mem, float* __restrict__ out_lu, int E, int N)
{
    __shared__ unsigned short sA[FB_GR * NKS * 512];
    __shared__ int   s_other[FB_MB];
    __shared__ int   s_j[FB_MB];
    __shared__ int   s_has[FB_MB];
    __shared__ float s_dt[FB_MB];

    const int tid   = threadIdx.x;
    const int node0 = blockIdx.x * FB_MB;

    if (tid < FB_MB) {
        int node = node0 + tid;
        int has = 0, j = 0, other = 0; float dt = 0.f;
        if (node < N) {
            int lu = last_update[node];
            int w  = win[node];
            int te = lu;
            if (w >= 0) {
                has = 1;
                int e = (w < E) ? w : (w - E);
                j = e;
                other = (w < E) ? dst[e] : src[e];
                te = t[e];
                dt = (float)(te - lu);
            }
            out_lu[node] = (float)(te > lu ? te : lu);
        }
        s_j[tid] = j; s_other[tid] = other; s_has[tid] = has; s_dt[tid] = dt;
    }
    __syncthreads();

    if (tid < 432) {
        const int nl    = tid % 48;
        const int c0    = tid / 48;
        const int node  = node0 + nl;
        const bool valid = node < N;
        const int has   = s_has[nl];
        const float* memN = memory + (size_t)node * H;
        const float* memO = memory + (size_t)s_other[nl] * H;
        const float* rawJ = raw_msg + (size_t)s_j[nl] * RD;
        const float dt  = s_dt[nl];
        const int grp = nl >> 4;
        const int row = nl & 15;

        float4 va[8], vb[8];
#pragma unroll
        for (int it = 0; it < 8; ++it) {
            const int cc = c0 + it * 9;
            va[it] = make_float4(0.f, 0.f, 0.f, 0.f); vb[it] = va[it];
            if (cc < 67) {
                const int c = cc + 13, kb = c * 8;
                if (c < 26)      { if (has)  { va[it] = ld4g(memO, kb - 104, 100); vb[it] = ld4g(memO, kb - 100, 100); } }
                else if (c < 48) { if (has)  { va[it] = ld4g(rawJ, kb - 208, RD ); vb[it] = ld4g(rawJ, kb - 204, RD ); } }
                else if (c < 64) { }
                else             { if (valid){ va[it] = ld4g(memN, kb - 512, 100); vb[it] = ld4g(memN, kb - 508, 100); } }
            }
        }
#pragma unroll
        for (int it = 0; it < 8; ++it) {
            const int cc = c0 + it * 9;
            if (cc < 67) {
                const int c = cc + 13;
                if (c >= 48 && c < 64 && has) {
                    const int lc = c * 8 - 384;
                    float vv[8];
#pragma unroll
                    for (int x = 0; x < 8; ++x) {
                        int col = lc + x;
                        vv[x] = (col < 100) ? __cosf(fmaf(dt, te_w[col], te_b[col])) : 0.f;
                    }
                    va[it] = make_float4(vv[0], vv[1], vv[2], vv[3]);
                    vb[it] = make_float4(vv[4], vv[5], vv[6], vv[7]);
                }
                int4 sv;
                sv.x = (int)pkbf(va[it].x, va[it].y);
                sv.y = (int)pkbf(va[it].z, va[it].w);
                sv.z = (int)pkbf(vb[it].x, vb[it].y);
                sv.w = (int)pkbf(vb[it].z, vb[it].w);
                {
                    const int ks = c >> 2, sub = c & 3;
                    *(int4*)&sA[((grp * NKS + ks) * 64 + sub * 16 + row) * 8] = sv;
                }
                if (c >= 64 && c < 77) {
                    int4 sm_;
                    sm_.x = has ? sv.x : 0; sm_.y = has ? sv.y : 0;
                    sm_.z = has ? sv.z : 0; sm_.w = has ? sv.w : 0;
                    const int cm = c - 64;
                    const int ks = cm >> 2, sub = cm & 3;
                    *(int4*)&sA[((grp * NKS + ks) * 64 + sub * 16 + row) * 8] = sm_;
                }
            }
        }
    }
    __syncthreads();

    const int wv   = tid >> 6;
    const int lane = tid & 63;
    const int lrow = lane & 15;
    const int lhi  = lane >> 4;

    f32x4 ar[FB_GR], az[FB_GR], an[FB_GR], ah[FB_GR];
#pragma unroll
    for (int m = 0; m < FB_GR; ++m) { ar[m] = (f32x4)0.f; az[m] = (f32x4)0.f; an[m] = (f32x4)0.f; ah[m] = (f32x4)0.f; }

    __builtin_amdgcn_s_setprio(1);
#pragma unroll
    for (int ks = 0; ks < NKS; ++ks) {
        short8 a0 = *(const short8*)&sA[(0 * NKS + ks) * 512 + lane * 8];
        short8 a1 = *(const short8*)&sA[(1 * NKS + ks) * 512 + lane * 8];
        short8 a2 = *(const short8*)&sA[(2 * NKS + ks) * 512 + lane * 8];
        short8 br = *(const short8*)&Bpack[(((size_t)(     wv) * NKS + ks) * 64 + lane) * 8];
        short8 bz = *(const short8*)&Bpack[(((size_t)( 7 + wv) * NKS + ks) * 64 + lane) * 8];
        short8 bn = (ks < 16)
                  ? *(const short8*)&Bpack[(((size_t)(14 + wv) * NKS + ks) * 64 + lane) * 8]
                  : *(const short8*)&Bpack[(((size_t)(21 + wv) * NKS + ks) * 64 + lane) * 8];
        ar[0] = mfma16(a0, br, ar[0]);  ar[1] = mfma16(a1, br, ar[1]);  ar[2] = mfma16(a2, br, ar[2]);
        az[0] = mfma16(a0, bz, az[0]);  az[1] = mfma16(a1, bz, az[1]);  az[2] = mfma16(a2, bz, az[2]);
        if (ks < 16) { an[0] = mfma16(a0, bn, an[0]);  an[1] = mfma16(a1, bn, an[1]);  an[2] = mfma16(a2, bn, an[2]); }
        else         { ah[0] = mfma16(a0, bn, ah[0]);  ah[1] = mfma16(a1, bn, ah[1]);  ah[2] = mfma16(a2, bn, ah[2]); }
    }
    __builtin_amdgcn_s_setprio(0);

    const int c = wv * 16 + lrow;
    if (c < 100) {
        const float br_ = b_ih[c]       + b_hh[c];
        const float bz_ = b_ih[c + 100] + b_hh[c + 100];
        const float bin = b_ih[c + 200];
        const float bhn = b_hh[c + 200];
        const int ksh = 16 + (c >> 5);
        const int qh  = (c >> 3) & 3;
        const int e   = c & 7;
#pragma unroll
        for (int m = 0; m < FB_GR; ++m) {
#pragma unroll
            for (int r = 0; r < 4; ++r) {
                const int node = node0 + m * 16 + lhi * 4 + r;
                if (node < N) {
                    const int rw = lhi * 4 + r;
                    const float h  = bf2f(sA[(m * NKS + ksh) * 512 + (qh * 16 + rw) * 8 + e]);
                    const float rg = frcp(1.f + __expf(-(ar[m][r] + br_)));
                    const float zg = frcp(1.f + __expf(-(az[m][r] + bz_)));
                    const float xn = an[m][r] + bin + rg * (ah[m][r] + bhn);
                    const float th = copysignf(1.f - 2.f * frcp(__expf(2.f * fabsf(xn)) + 1.f), xn);
                    out_mem[(size_t)node * H + c] = (1.f - zg) * th + zg * h;
                }
            }
        }
    }
}

extern "C" void kernel_launch(void* const* d_in, const int* in_sizes, int n_in,
                              void* d_out, int out_size, void* d_ws, size_t ws_size,
                              hipStream_t stream)
{
    const int*   src         = (const int*)d_in[0];
    const int*   dst         = (const int*)d_in[1];
    const int*   t           = (const int*)d_in[2];
    const float* raw_msg     = (const float*)d_in[3];
    const float* memory      = (const float*)d_in[4];
    const int*   last_update = (const int*)d_in[5];
    const float* te_w        = (const float*)d_in[6];
    const float* te_b        = (const float*)d_in[7];
    const float* w_ih        = (const float*)d_in[8];
    const float* w_hh        = (const float*)d_in[9];
    const float* b_ih        = (const float*)d_in[10];
    const float* b_hh        = (const float*)d_in[11];

    const int E = in_sizes[0];   // 100000
    const int N = in_sizes[5];   // 200000

    float* out    = (float*)d_out;
    float* out_lu = out + (size_t)N * H;

    char* ws = (char*)d_ws;
    int* maxt = (int*)ws;
    int* win  = maxt + N;
    unsigned short* Bpack = (unsigned short*)(win + N);
    int4* meta = (int4*)(Bpack + BPK_N);
    unsigned short* zb   = (unsigned short*)(meta + N);
    unsigned short* memB = zb + 256;
    unsigned short* rawB = memB + (size_t)N * MSTR + 32;
    const size_t need = (size_t)((char*)(rawB + (size_t)E * RSTR) - ws) + 64;

    k_init<<<(N + 255) / 256, 256, 0, stream>>>(maxt, win, (int*)zb, N);
    k_prep<<<(BPK_N + 255) / 256, 256, 0, stream>>>(w_ih, w_hh, Bpack);
    k_maxt<<<(E + 255) / 256, 256, 0, stream>>>(src, dst, t, maxt, E);
    k_win <<<(E + 255) / 256, 256, 0, stream>>>(src, dst, t, maxt, win, E);

    if (ws_size >= need) {
        const int ncvt = N * 13 + E * 22;
        k_cvt<<<(ncvt + 255) / 256, 256, 0, stream>>>(memory, raw_msg, memB, rawB, N, E);
        k_meta<<<(N + 255) / 256, 256, 0, stream>>>(src, dst, t, last_update, win, meta, out_lu, E, N);
        k_gru2<<<(N + MB - 1) / MB, BLK, 0, stream>>>(memB, rawB, te_w, te_b, b_ih, b_hh,
                                                      meta, zb, Bpack, out, N);
    } else {
        k_gru_fused<<<(N + FB_MB - 1) / FB_MB, BLK, 0, stream>>>(src, dst, t, raw_msg, memory, last_update,
                                                                 te_w, te_b, b_ih, b_hh, win, Bpack,
                                                                 out, out_lu, E, N);
    }
}

// Round 14
// 196.563 us; speedup vs baseline: 3.6294x; 1.0469x over previous
//
#include <hip/hip_runtime.h>
#include <math.h>

typedef __attribute__((ext_vector_type(8))) short  short8;
typedef __attribute__((ext_vector_type(4))) float  f32x4;

// Problem constants: N=200000, E=100000, H=100, R=172, T=100
static constexpr int H     = 100;
static constexpr int RD    = 172;
static constexpr int WK    = 472;
static constexpr int MSTR  = 104;            // memB row stride (bf16)
static constexpr int RSTR  = 176;            // rawB row stride (bf16)
// Padded K layout: [0,104) mem[node] msg | [104,208) mem[other] | [208,384) raw
//                  [384,512) tenc | [512,640) mem[node] hh
static constexpr int NKS   = 20;
static constexpr int MB    = 32;             // nodes per block (2 x 16-row groups)
static constexpr int GRPS  = 2;
static constexpr int BLK   = 448;            // 7 waves; wave wv owns cols wv*16..+15
static constexpr int NTT   = 28;
static constexpr int BPK_N = NTT * NKS * 64 * 8;   // 286720 bf16

// fallback (r7-style) constants
static constexpr int FB_MB = 48;
static constexpr int FB_GR = 3;

__device__ inline unsigned short f2bf(float x) {
    union { float f; unsigned u; } v; v.f = x;
    return (unsigned short)((v.u + 0x7FFFu + ((v.u >> 16) & 1u)) >> 16);
}
__device__ inline float bf2f(unsigned short b) {
    union { unsigned u; float f; } v; v.u = ((unsigned)b) << 16;
    return v.f;
}
__device__ inline unsigned pkbf(float a, float b) {
    unsigned r;
    asm("v_cvt_pk_bf16_f32 %0, %1, %2" : "=v"(r) : "v"(a), "v"(b));
    return r;
}
__device__ inline float frcp(float x) {
    float r;
    asm("v_rcp_f32 %0, %1" : "=v"(r) : "v"(x));
    return r;
}
__device__ inline f32x4 mfma16(short8 a, short8 b, f32x4 c) {
    return __builtin_amdgcn_mfma_f32_16x16x32_bf16(a, b, c, 0, 0, 0);
}
__device__ inline float4 ld4g(const float* base, int lc, int limit) {
    if (lc + 4 <= limit) return *(const float4*)(base + lc);
    return make_float4(0.f, 0.f, 0.f, 0.f);
}
__device__ inline void gl16(const unsigned short* g, unsigned short* l) {
    __builtin_amdgcn_global_load_lds(
        (const __attribute__((address_space(1))) void*)g,
        (__attribute__((address_space(3))) void*)l, 16, 0, 0);
}

// ---------------- k_pre: init + weight prep + optional bf16 conversion ----------------
// docvt=0: only prep + init (fallback path). docvt=1: also memB/rawB conversion.
__global__ __launch_bounds__(256) void k_pre(
    const float* __restrict__ mem, const float* __restrict__ raw,
    const float* __restrict__ w_ih, const float* __restrict__ w_hh,
    unsigned short* __restrict__ memB, unsigned short* __restrict__ rawB,
    unsigned short* __restrict__ B, int* __restrict__ maxt, int* __restrict__ win,
    int* __restrict__ zb, int N, int E, int docvt)
{
    int i = blockIdx.x * 256 + threadIdx.x;
    if (docvt) {
        const int nm = N * 13;
        if (i < nm) {
            int row = i / 13, o = (i - row * 13) * 8;
            float4 a = ld4g(mem + (size_t)row * 100, o, 100);
            float4 b = ld4g(mem + (size_t)row * 100, o + 4, 100);
            int4 s; s.x = (int)pkbf(a.x, a.y); s.y = (int)pkbf(a.z, a.w);
            s.z = (int)pkbf(b.x, b.y); s.w = (int)pkbf(b.z, b.w);
            *(int4*)&memB[(size_t)row * MSTR + o] = s;
            return;
        }
        i -= nm;
        const int nr = E * 22;
        if (i < nr) {
            int row = i / 22, o = (i - row * 22) * 8;
            float4 a = ld4g(raw + (size_t)row * 172, o, 172);
            float4 b = ld4g(raw + (size_t)row * 172, o + 4, 172);
            int4 s; s.x = (int)pkbf(a.x, a.y); s.y = (int)pkbf(a.z, a.w);
            s.z = (int)pkbf(b.x, b.y); s.w = (int)pkbf(b.z, b.w);
            *(int4*)&rawB[(size_t)row * RSTR + o] = s;
            return;
        }
        i -= nr;
    }
    if (i < BPK_N) {
        int idx  = i;
        int jj   = idx & 7;
        int lane = (idx >> 3) & 63;
        int rest = idx >> 9;
        int ks   = rest % NKS;
        int tile = rest / NKS;
        int kk   = ks * 32 + ((lane >> 4) << 3) + jj;
        float v = 0.f;
        if (tile < 21) {
            int gate = tile / 7;
            int tcol = (tile % 7) * 16 + (lane & 15);
            if (tcol < 100) {
                if (kk < 512) {
                    int col = -1;
                    if (kk < 100)                   col = kk;
                    else if (kk >= 104 && kk < 204) col = kk - 4;
                    else if (kk >= 208 && kk < 380) col = kk - 8;
                    else if (kk >= 384 && kk < 484) col = kk - 12;
                    if (col >= 0) v = w_ih[(gate * 100 + tcol) * WK + col];
                } else {
                    int khh = kk - 512;
                    if (gate < 2 && khh < 100)
                        v = w_hh[(gate * 100 + tcol) * H + khh];
                }
            }
        } else {
            int tcol = (tile - 21) * 16 + (lane & 15);
            int khh  = kk - 512;
            if (tcol < 100 && khh >= 0 && khh < 100)
                v = w_hh[(200 + tcol) * H + khh];
        }
        B[idx] = f2bf(v);
        return;
    }
    i -= BPK_N;
    if (i < N) { maxt[i] = (int)0x80000000; win[i] = -1; }
    if (i < 128) zb[i] = 0;
}

// ---------------- aggregation ----------------
__global__ __launch_bounds__(256) void k_maxt(const int* __restrict__ src, const int* __restrict__ dst,
                                              const int* __restrict__ t, int* __restrict__ maxt, int E) {
    int j = blockIdx.x * blockDim.x + threadIdx.x;
    if (j < E) {
        int tj = t[j];
        atomicMax(&maxt[src[j]], tj);
        atomicMax(&maxt[dst[j]], tj);
    }
}
__global__ __launch_bounds__(256) void k_win(const int* __restrict__ src, const int* __restrict__ dst,
                                             const int* __restrict__ t, const int* __restrict__ maxt,
                                             int* __restrict__ win, int E) {
    int j = blockIdx.x * blockDim.x + threadIdx.x;
    if (j < E) {
        int tj = t[j];
        int s = src[j], d = dst[j];
        if (maxt[s] == tj) atomicMax(&win[s], j);
        if (maxt[d] == tj) atomicMax(&win[d], j + E);
    }
}
__global__ __launch_bounds__(256) void k_meta(const int* __restrict__ src, const int* __restrict__ dst,
                                              const int* __restrict__ t, const int* __restrict__ last_update,
                                              const int* __restrict__ win, int4* __restrict__ meta,
                                              float* __restrict__ out_lu, int E, int N) {
    int i = blockIdx.x * blockDim.x + threadIdx.x;
    if (i >= N) return;
    int lu = last_update[i], w = win[i];
    int j = 0, other = 0, has = 0, te = lu; float dt = 0.f;
    if (w >= 0) {
        has = 1;
        int e = (w < E) ? w : (w - E);
        j = e;
        other = (w < E) ? dst[e] : src[e];
        te = t[e];
        dt = (float)(te - lu);
    }
    out_lu[i] = (float)(te > lu ? te : lu);
    int4 m; m.x = j; m.y = other; m.z = has; m.w = __float_as_int(dt);
    meta[i] = m;
}

#define LB(tile, ks) (*(const short8*)&Bpack[(((size_t)(tile) * NKS + (ks)) * 64 + lane) * 8])

// ---------------- fused GRU: gl16 staging + B-pipelined MFMA ----------------
__global__ __launch_bounds__(BLK, 4) void k_gru2(
    const unsigned short* __restrict__ memB, const unsigned short* __restrict__ rawB,
    const float* __restrict__ te_w, const float* __restrict__ te_b,
    const float* __restrict__ b_ih, const float* __restrict__ b_hh,
    const int4* __restrict__ meta, const unsigned short* __restrict__ zb,
    const unsigned short* __restrict__ Bpack,
    float* __restrict__ out_mem, int N)
{
    __shared__ unsigned short sA[GRPS * NKS * 512];   // 40960 B

    const int tid  = threadIdx.x;
    const int wv   = tid >> 6;
    const int lane = tid & 63;
    const int q    = lane >> 4;
    const int row  = lane & 15;
    const int node0 = blockIdx.x * MB;

#pragma unroll
    for (int g = 0; g < GRPS; ++g) {
        const int node_g = node0 + g * 16 + row;
        const bool val = node_g < N;
        const int4 m = val ? meta[node_g] : make_int4(0, 0, 0, 0);
        const bool has = m.z != 0;
        const float dt = __int_as_float(m.w);
        const unsigned short* pmm = has ? memB + (size_t)node_g * MSTR : zb;
        const unsigned short* pot = has ? memB + (size_t)m.y * MSTR   : zb;
        const unsigned short* prw = has ? rawB + (size_t)m.x * RSTR   : zb;
        const unsigned short* phh = val ? memB + (size_t)node_g * MSTR : zb;

#pragma unroll
        for (int ii = 0; ii < 3; ++ii) {
            const int ks = wv + 7 * ii;
            if (ks < NKS && (ks < 12 || ks >= 16)) {
                const int k0 = ks * 32 + q * 8;
                const unsigned short* s =
                    (k0 < 104) ? pmm + k0 :
                    (k0 < 208) ? pot + (k0 - 104) :
                    (k0 < 384) ? prw + (k0 - 208) :
                                 phh + (k0 - 512);
                gl16(s, &sA[(g * NKS + ks) * 512]);
            }
        }
#pragma unroll
        for (int ii = 0; ii < 3; ++ii) {
            const int ks = wv + 7 * ii;
            if (ks >= 12 && ks < 16) {
                const int o = (ks - 12) * 32 + q * 8;
                float4 w0 = ld4g(te_w, o, 100), w1 = ld4g(te_w, o + 4, 100);
                float4 c0 = ld4g(te_b, o, 100), c1 = ld4g(te_b, o + 4, 100);
                const float hf = has ? 1.f : 0.f;
                float v0 = hf * __cosf(fmaf(dt, w0.x, c0.x));
                float v1 = hf * __cosf(fmaf(dt, w0.y, c0.y));
                float v2 = hf * __cosf(fmaf(dt, w0.z, c0.z));
                float v3 = hf * __cosf(fmaf(dt, w0.w, c0.w));
                float v4 = hf * __cosf(fmaf(dt, w1.x, c1.x));
                float v5 = hf * __cosf(fmaf(dt, w1.y, c1.y));
                float v6 = hf * __cosf(fmaf(dt, w1.z, c1.z));
                float v7 = hf * __cosf(fmaf(dt, w1.w, c1.w));
                int4 sv;
                sv.x = (int)pkbf(v0, v1); sv.y = (int)pkbf(v2, v3);
                sv.z = (int)pkbf(v4, v5); sv.w = (int)pkbf(v6, v7);
                *(int4*)&sA[(g * NKS + ks) * 512 + lane * 8] = sv;
            }
        }
    }
    __syncthreads();

    f32x4 ar[GRPS], az[GRPS], an[GRPS], ah[GRPS];
#pragma unroll
    for (int m = 0; m < GRPS; ++m) { ar[m] = (f32x4)0.f; az[m] = (f32x4)0.f; an[m] = (f32x4)0.f; ah[m] = (f32x4)0.f; }

    short8 cr = LB(wv, 0);
    short8 cz = LB(7 + wv, 0);
    short8 cn = LB(14 + wv, 0);

    __builtin_amdgcn_s_setprio(1);
#pragma unroll
    for (int ks = 0; ks < NKS; ++ks) {
        short8 nr = cr, nz = cz, nn2 = cn;
        if (ks + 1 < NKS) {
            nr  = LB(wv, ks + 1);
            nz  = LB(7 + wv, ks + 1);
            nn2 = LB((ks + 1 < 16) ? (14 + wv) : (21 + wv), ks + 1);
        }
        short8 a0 = *(const short8*)&sA[(0 * NKS + ks) * 512 + lane * 8];
        short8 a1 = *(const short8*)&sA[(1 * NKS + ks) * 512 + lane * 8];
        __builtin_amdgcn_sched_barrier(0);
        ar[0] = mfma16(a0, cr, ar[0]);  ar[1] = mfma16(a1, cr, ar[1]);
        az[0] = mfma16(a0, cz, az[0]);  az[1] = mfma16(a1, cz, az[1]);
        if (ks < 16) { an[0] = mfma16(a0, cn, an[0]);  an[1] = mfma16(a1, cn, an[1]); }
        else         { ah[0] = mfma16(a0, cn, ah[0]);  ah[1] = mfma16(a1, cn, ah[1]); }
        cr = nr; cz = nz; cn = nn2;
    }
    __builtin_amdgcn_s_setprio(0);

    const int c = wv * 16 + row;
    if (c < 100) {
        const float br_ = b_ih[c]       + b_hh[c];
        const float bz_ = b_ih[c + 100] + b_hh[c + 100];
        const float bin = b_ih[c + 200];
        const float bhn = b_hh[c + 200];
        const int ksh = 16 + (c >> 5);
        const int qh  = (c >> 3) & 3;
        const int e   = c & 7;
#pragma unroll
        for (int m = 0; m < GRPS; ++m) {
#pragma unroll
            for (int r = 0; r < 4; ++r) {
                const int node = node0 + m * 16 + q * 4 + r;
                if (node < N) {
                    const int rw = q * 4 + r;
                    const float h  = bf2f(sA[(m * NKS + ksh) * 512 + (qh * 16 + rw) * 8 + e]);
                    const float rg = frcp(1.f + __expf(-(ar[m][r] + br_)));
                    const float zg = frcp(1.f + __expf(-(az[m][r] + bz_)));
                    const float xn = an[m][r] + bin + rg * (ah[m][r] + bhn);
                    const float th = copysignf(1.f - 2.f * frcp(__expf(2.f * fabsf(xn)) + 1.f), xn);
                    out_mem[(size_t)node * H + c] = (1.f - zg) * th + zg * h;
                }
            }
        }
    }
}

// ---------------- fused fallback (r7-style) if ws too small ----------------
__global__ __launch_bounds__(BLK, 4) void k_gru_fused(
    const int* __restrict__ src, const int* __restrict__ dst, const int* __restrict__ t,
    const float* __restrict__ raw_msg, const float* __restrict__ memory,
    const int* __restrict__ last_update, const float* __restrict__ te_w,
    const float* __restrict__ te_b, const float* __restrict__ b_ih,
    const float* __restrict__ b_hh, const int* __restrict__ win,
    const unsigned short* __restrict__ Bpack,
    float* __restrict__ out_mem, float* __restrict__ out_lu, int E, int N)
{
    __shared__ unsigned short sA[FB_GR * NKS * 512];
    __shared__ int   s_other[FB_MB];
    __shared__ int   s_j[FB_MB];
    __shared__ int   s_has[FB_MB];
    __shared__ float s_dt[FB_MB];

    const int tid   = threadIdx.x;
    const int node0 = blockIdx.x * FB_MB;

    if (tid < FB_MB) {
        int node = node0 + tid;
        int has = 0, j = 0, other = 0; float dt = 0.f;
        if (node < N) {
            int lu = last_update[node];
            int w  = win[node];
            int te = lu;
            if (w >= 0) {
                has = 1;
                int e = (w < E) ? w : (w - E);
                j = e;
                other = (w < E) ? dst[e] : src[e];
                te = t[e];
                dt = (float)(te - lu);
            }
            out_lu[node] = (float)(te > lu ? te : lu);
        }
        s_j[tid] = j; s_other[tid] = other; s_has[tid] = has; s_dt[tid] = dt;
    }
    __syncthreads();

    if (tid < 432) {
        const int nl    = tid % 48;
        const int c0    = tid / 48;
        const int node  = node0 + nl;
        const bool valid = node < N;
        const int has   = s_has[nl];
        const float* memN = memory + (size_t)node * H;
        const float* memO = memory + (size_t)s_other[nl] * H;
        const float* rawJ = raw_msg + (size_t)s_j[nl] * RD;
        const float dt  = s_dt[nl];
        const int grp = nl >> 4;
        const int row = nl & 15;

        float4 va[8], vb[8];
#pragma unroll
        for (int it = 0; it < 8; ++it) {
            const int cc = c0 + it * 9;
            va[it] = make_float4(0.f, 0.f, 0.f, 0.f); vb[it] = va[it];
            if (cc < 67) {
                const int c = cc + 13, kb = c * 8;
                if (c < 26)      { if (has)  { va[it] = ld4g(memO, kb - 104, 100); vb[it] = ld4g(memO, kb - 100, 100); } }
                else if (c < 48) { if (has)  { va[it] = ld4g(rawJ, kb - 208, RD ); vb[it] = ld4g(rawJ, kb - 204, RD ); } }
                else if (c < 64) { }
                else             { if (valid){ va[it] = ld4g(memN, kb - 512, 100); vb[it] = ld4g(memN, kb - 508, 100); } }
            }
        }
#pragma unroll
        for (int it = 0; it < 8; ++it) {
            const int cc = c0 + it * 9;
            if (cc < 67) {
                const int c = cc + 13;
                if (c >= 48 && c < 64 && has) {
                    const int lc = c * 8 - 384;
                    float vv[8];
#pragma unroll
                    for (int x = 0; x < 8; ++x) {
                        int col = lc + x;
                        vv[x] = (col < 100) ? __cosf(fmaf(dt, te_w[col], te_b[col])) : 0.f;
                    }
                    va[it] = make_float4(vv[0], vv[1], vv[2], vv[3]);
                    vb[it] = make_float4(vv[4], vv[5], vv[6], vv[7]);
                }
                int4 sv;
                sv.x = (int)pkbf(va[it].x, va[it].y);
                sv.y = (int)pkbf(va[it].z, va[it].w);
                sv.z = (int)pkbf(vb[it].x, vb[it].y);
                sv.w = (int)pkbf(vb[it].z, vb[it].w);
                {
                    const int ks = c >> 2, sub = c & 3;
                    *(int4*)&sA[((grp * NKS + ks) * 64 + sub * 16 + row) * 8] = sv;
                }
                if (c >= 64 && c < 77) {
                    int4 sm_;
                    sm_.x = has ? sv.x : 0; sm_.y = has ? sv.y : 0;
                    sm_.z = has ? sv.z : 0; sm_.w = has ? sv.w : 0;
                    const int cm = c - 64;
                    const int ks = cm >> 2, sub = cm & 3;
                    *(int4*)&sA[((grp * NKS + ks) * 64 + sub * 16 + row) * 8] = sm_;
                }
            }
        }
    }
    __syncthreads();

    const int wv   = tid >> 6;
    const int lane = tid & 63;
    const int lrow = lane & 15;
    const int lhi  = lane >> 4;

    f32x4 ar[FB_GR], az[FB_GR], an[FB_GR], ah[FB_GR];
#pragma unroll
    for (int m = 0; m < FB_GR; ++m) { ar[m] = (f32x4)0.f; az[m] = (f32x4)0.f; an[m] = (f32x4)0.f; ah[m] = (f32x4)0.f; }

    __builtin_amdgcn_s_setprio(1);
#pragma unroll
    for (int ks = 0; ks < NKS; ++ks) {
        short8 a0 = *(const short8*)&sA[(0 * NKS + ks) * 512 + lane * 8];
        short8 a1 = *(const short8*)&sA[(1 * NKS + ks) * 512 + lane * 8];
        short8 a2 = *(const short8*)&sA[(2 * NKS + ks) * 512 + lane * 8];
        short8 br = LB(wv, ks);
        short8 bz = LB(7 + wv, ks);
        short8 bn = (ks < 16) ? LB(14 + wv, ks) : LB(21 + wv, ks);
        ar[0] = mfma16(a0, br, ar[0]);  ar[1] = mfma16(a1, br, ar[1]);  ar[2] = mfma16(a2, br, ar[2]);
        az[0] = mfma16(a0, bz, az[0]);  az[1] = mfma16(a1, bz, az[1]);  az[2] = mfma16(a2, bz, az[2]);
        if (ks < 16) { an[0] = mfma16(a0, bn, an[0]);  an[1] = mfma16(a1, bn, an[1]);  an[2] = mfma16(a2, bn, an[2]); }
        else         { ah[0] = mfma16(a0, bn, ah[0]);  ah[1] = mfma16(a1, bn, ah[1]);  ah[2] = mfma16(a2, bn, ah[2]); }
    }
    __builtin_amdgcn_s_setprio(0);

    const int c = wv * 16 + lrow;
    if (c < 100) {
        const float br_ = b_ih[c]       + b_hh[c];
        const float bz_ = b_ih[c + 100] + b_hh[c + 100];
        const float bin = b_ih[c + 200];
        const float bhn = b_hh[c + 200];
        const int ksh = 16 + (c >> 5);
        const int qh  = (c >> 3) & 3;
        const int e   = c & 7;
#pragma unroll
        for (int m = 0; m < FB_GR; ++m) {
#pragma unroll
            for (int r = 0; r < 4; ++r) {
                const int node = node0 + m * 16 + lhi * 4 + r;
                if (node < N) {
                    const int rw = lhi * 4 + r;
                    const float h  = bf2f(sA[(m * NKS + ksh) * 512 + (qh * 16 + rw) * 8 + e]);
                    const float rg = frcp(1.f + __expf(-(ar[m][r] + br_)));
                    const float zg = frcp(1.f + __expf(-(az[m][r] + bz_)));
                    const float xn = an[m][r] + bin + rg * (ah[m][r] + bhn);
                    const float th = copysignf(1.f - 2.f * frcp(__expf(2.f * fabsf(xn)) + 1.f), xn);
                    out_mem[(size_t)node * H + c] = (1.f - zg) * th + zg * h;
                }
            }
        }
    }
}

extern "C" void kernel_launch(void* const* d_in, const int* in_sizes, int n_in,
                              void* d_out, int out_size, void* d_ws, size_t ws_size,
                              hipStream_t stream)
{
    const int*   src         = (const int*)d_in[0];
    const int*   dst         = (const int*)d_in[1];
    const int*   t           = (const int*)d_in[2];
    const float* raw_msg     = (const float*)d_in[3];
    const float* memory      = (const float*)d_in[4];
    const int*   last_update = (const int*)d_in[5];
    const float* te_w        = (const float*)d_in[6];
    const float* te_b        = (const float*)d_in[7];
    const float* w_ih        = (const float*)d_in[8];
    const float* w_hh        = (const float*)d_in[9];
    const float* b_ih        = (const float*)d_in[10];
    const float* b_hh        = (const float*)d_in[11];

    const int E = in_sizes[0];   // 100000
    const int N = in_sizes[5];   // 200000

    float* out    = (float*)d_out;
    float* out_lu = out + (size_t)N * H;

    char* ws = (char*)d_ws;
    int* maxt = (int*)ws;
    int* win  = maxt + N;
    unsigned short* Bpack = (unsigned short*)(win + N);
    int4* meta = (int4*)(Bpack + BPK_N);
    unsigned short* zb   = (unsigned short*)(meta + N);
    unsigned short* memB = zb + 256;
    unsigned short* rawB = memB + (size_t)N * MSTR + 32;
    const size_t need = (size_t)((char*)(rawB + (size_t)E * RSTR) - ws) + 64;

    if (ws_size >= need) {
        const int npre = N * 13 + E * 22 + BPK_N + N;
        k_pre <<<(npre + 255) / 256, 256, 0, stream>>>(memory, raw_msg, w_ih, w_hh,
                                                       memB, rawB, Bpack, maxt, win, (int*)zb, N, E, 1);
        k_maxt<<<(E + 255) / 256, 256, 0, stream>>>(src, dst, t, maxt, E);
        k_win <<<(E + 255) / 256, 256, 0, stream>>>(src, dst, t, maxt, win, E);
        k_meta<<<(N + 255) / 256, 256, 0, stream>>>(src, dst, t, last_update, win, meta, out_lu, E, N);
        k_gru2<<<(N + MB - 1) / MB, BLK, 0, stream>>>(memB, rawB, te_w, te_b, b_ih, b_hh,
                                                      meta, zb, Bpack, out, N);
    } else {
        const int npre = BPK_N + N;                       // docvt=0: prep + init only
        k_pre <<<(npre + 255) / 256, 256, 0, stream>>>(memory, raw_msg, w_ih, w_hh,
                                                       Bpack, Bpack, Bpack, maxt, win, (int*)zb, N, E, 0);
        k_maxt<<<(E + 255) / 256, 256, 0, stream>>>(src, dst, t, maxt, E);
        k_win <<<(E + 255) / 256, 256, 0, stream>>>(src, dst, t, maxt, win, E);
        k_gru_fused<<<(N + FB_MB - 1) / FB_MB, BLK, 0, stream>>>(src, dst, t, raw_msg, memory, last_update,
                                                                 te_w, te_b, b_ih, b_hh, win, Bpack,
                                                                 out, out_lu, E, N);
    }
}